// Round 4
// baseline (469.258 us; speedup 1.0000x reference)
//
#include <hip/hip_runtime.h>
#include <hip/hip_bf16.h>

typedef __attribute__((ext_vector_type(8))) short short8;
typedef __attribute__((ext_vector_type(4))) float f32x4;

#define DEV __device__ __forceinline__

DEV float bf2f(ushort u){ union { float f; unsigned int i; } x; x.i = ((unsigned int)u)<<16; return x.f; }
DEV ushort f2bf(float f){ union { float fl; unsigned int i; } x; x.fl = f; unsigned int r = x.i + 0x7fffu + ((x.i>>16)&1u); return (ushort)(r>>16); }

DEV void gl2lds16(const ushort* g, ushort* l){
  __builtin_amdgcn_global_load_lds((const __attribute__((address_space(1))) void*)g,
                                   (__attribute__((address_space(3))) void*)l, 16, 0, 0);
}

// ---------------- fp32 -> bf16 convert (Er only) ----------------
__global__ void cvt_f2b(const float* __restrict__ in, ushort* __restrict__ out, int n){
  int i = blockIdx.x*blockDim.x + threadIdx.x;
  int stride = gridDim.x*blockDim.x;
  for (; i < n; i += stride) out[i] = f2bf(in[i]);
}

// ---------------- fp32 [K][N] -> bf16 [N][K] tiled transpose ----------------
__global__ __launch_bounds__(256) void wt_cvt(const float* __restrict__ in, ushort* __restrict__ out,
                                              int K, int N){
  const int n0 = blockIdx.x*64, k0 = blockIdx.y*64;
  __shared__ float T[64][65];
  const int tid = threadIdx.x;
  const int r = tid>>4, c = (tid&15)*4;
  #pragma unroll
  for (int p=0;p<4;p++){
    float4 v = *(const float4*)&in[(size_t)(k0 + p*16 + r)*N + n0 + c];
    T[p*16+r][c+0]=v.x; T[p*16+r][c+1]=v.y; T[p*16+r][c+2]=v.z; T[p*16+r][c+3]=v.w;
  }
  __syncthreads();
  #pragma unroll
  for (int p=0;p<4;p++){
    int n = p*16 + r;
    ushort u0 = f2bf(T[c+0][n]), u1 = f2bf(T[c+1][n]), u2 = f2bf(T[c+2][n]), u3 = f2bf(T[c+3][n]);
    ushort4 u = make_ushort4(u0,u1,u2,u3);
    *(ushort4*)&out[(size_t)(n0+n)*K + k0 + c] = u;
  }
}

// ---------------- V transpose: qkv V-part [n][hd] -> Vt [(bh*64+hd)][n] ----------------
__global__ __launch_bounds__(256) void vt_k(const ushort* __restrict__ qkv, ushort* __restrict__ vt){
  const int bh = blockIdx.y; const int b = bh>>4, h = bh&15;
  const int n0 = blockIdx.x*64;
  __shared__ ushort T[64][66];
  const int tid = threadIdx.x;
  const int r = tid>>3, c8 = (tid&7)*8;
  #pragma unroll
  for (int p=0;p<2;p++){
    int row = p*32 + r;
    short8 v = *(const short8*)&qkv[(size_t)(b*1024 + n0 + row)*3072 + 2048 + h*64 + c8];
    #pragma unroll
    for (int i=0;i<8;i++) T[row][c8+i] = ((ushort*)&v)[i];
  }
  __syncthreads();
  #pragma unroll
  for (int p=0;p<2;p++){
    int d = p*32 + r;
    union { ushort u[8]; short8 v; } o;
    #pragma unroll
    for (int i=0;i<8;i++) o.u[i] = T[c8+i][d];
    *(short8*)&vt[(size_t)(bh*64 + d)*1024 + n0 + c8] = o.v;
  }
}

// ---------------- LayerNorm over C=1024, one row per block ----------------
__global__ __launch_bounds__(256) void ln_rows(const float* __restrict__ in,
                                               const float* __restrict__ g,
                                               const float* __restrict__ bta,
                                               ushort* __restrict__ out){
  int row = blockIdx.x; int tid = threadIdx.x;
  const float* x = in + (size_t)row*1024;
  float v[4]; float s = 0.f;
  #pragma unroll
  for (int i=0;i<4;i++){ v[i] = x[tid + 256*i]; s += v[i]; }
  __shared__ float rbuf[256];
  rbuf[tid] = s; __syncthreads();
  for (int off=128; off>0; off>>=1){ if (tid<off) rbuf[tid]+=rbuf[tid+off]; __syncthreads(); }
  float mean = rbuf[0] * (1.f/1024.f);
  __syncthreads();
  float s2 = 0.f;
  #pragma unroll
  for (int i=0;i<4;i++){ float d=v[i]-mean; s2 += d*d; }
  rbuf[tid] = s2; __syncthreads();
  for (int off=128; off>0; off>>=1){ if (tid<off) rbuf[tid]+=rbuf[tid+off]; __syncthreads(); }
  float var = rbuf[0] * (1.f/1024.f);
  float rstd = rsqrtf(var + 1e-5f);
  #pragma unroll
  for (int i=0;i<4;i++){ int c = tid+256*i; out[(size_t)row*1024+c] = f2bf((v[i]-mean)*rstd*g[c]+bta[c]); }
}

// ---------------- time-embedding GEMM ----------------
__global__ __launch_bounds__(256) void tq_gemm2(const float* __restrict__ t, const float* __restrict__ tw,
                                                const float* __restrict__ tb, float* __restrict__ tq){
  const int tid = threadIdx.x;
  const int j = blockIdx.x*64 + (tid & 63);
  const int sl = tid >> 6;
  float acc[4] = {0.f,0.f,0.f,0.f};
  for (int k = sl*64; k < sl*64+64; ++k){
    float wv = tw[(size_t)k*3072 + j];
    #pragma unroll
    for (int b=0;b<4;b++) acc[b] = fmaf(t[b*256+k], wv, acc[b]);
  }
  __shared__ float red[4][4][64];
  #pragma unroll
  for (int b=0;b<4;b++) red[sl][b][tid&63] = acc[b];
  __syncthreads();
  if (sl == 0){
    #pragma unroll
    for (int b=0;b<4;b++)
      tq[b*3072 + j] = red[0][b][tid&63] + red[1][b][tid&63] + red[2][b][tid&63] + red[3][b][tid&63] + tb[j];
  }
}

// ---------------- m97-style 128x128 GEMM: BK=32, linear LDS, global_load_lds, XCD swizzle ----------------
template<int EPI>
__global__ __launch_bounds__(256) void gemm3(
    const ushort* __restrict__ A, const ushort* __restrict__ Bt,
    const float* __restrict__ bias, const float* __restrict__ extra,
    ushort* __restrict__ outb, float* __restrict__ outf,
    int M, int N, int K, int nbx)
{
  __shared__ __align__(16) ushort Al[128*32];
  __shared__ __align__(16) ushort Bl[128*32];
  const int nwg = gridDim.x, cpx = nwg >> 3;
  const int bid = blockIdx.x;
  const int swz = (bid & 7)*cpx + (bid >> 3);
  const int m0 = (swz / nbx)*128, n0 = (swz % nbx)*128;
  const int tid = threadIdx.x, lane = tid & 63, wid = tid >> 6;
  const int wm = (wid&1)*64, wn = (wid>>1)*64;
  const int l15 = lane&15, l4 = lane>>4;
  f32x4 acc[4][4];
  #pragma unroll
  for (int i=0;i<4;i++)
    #pragma unroll
    for (int jx=0;jx<4;jx++){ acc[i][jx][0]=0.f; acc[i][jx][1]=0.f; acc[i][jx][2]=0.f; acc[i][jx][3]=0.f; }
  const int ch0 = tid, ch1 = 256 + tid;
  const ushort* a0p = A  + (size_t)(m0 + (ch0>>2))*K + (ch0&3)*8;
  const ushort* a1p = A  + (size_t)(m0 + (ch1>>2))*K + (ch1&3)*8;
  const ushort* b0p = Bt + (size_t)(n0 + (ch0>>2))*K + (ch0&3)*8;
  const ushort* b1p = Bt + (size_t)(n0 + (ch1>>2))*K + (ch1&3)*8;
  ushort* la0 = &Al[ch0*8]; ushort* la1 = &Al[ch1*8];
  ushort* lb0 = &Bl[ch0*8]; ushort* lb1 = &Bl[ch1*8];
  for (int k0=0; k0<K; k0+=32){
    __syncthreads();
    gl2lds16(a0p + k0, la0);
    gl2lds16(a1p + k0, la1);
    gl2lds16(b0p + k0, lb0);
    gl2lds16(b1p + k0, lb1);
    __syncthreads();
    short8 af[4], bfr[4];
    #pragma unroll
    for (int mi=0;mi<4;mi++) af[mi]  = *(const short8*)&Al[(wm + mi*16 + l15)*32 + l4*8];
    #pragma unroll
    for (int nj=0;nj<4;nj++) bfr[nj] = *(const short8*)&Bl[(wn + nj*16 + l15)*32 + l4*8];
    #pragma unroll
    for (int mi=0;mi<4;mi++)
      #pragma unroll
      for (int nj=0;nj<4;nj++)
        acc[mi][nj] = __builtin_amdgcn_mfma_f32_16x16x32_bf16(af[mi], bfr[nj], acc[mi][nj], 0,0,0);
  }
  #pragma unroll
  for (int mi=0;mi<4;mi++)
    #pragma unroll
    for (int nj=0;nj<4;nj++)
      #pragma unroll
      for (int j=0;j<4;j++){
        int row = m0 + wm + mi*16 + l4*4 + j;
        int col = n0 + wn + nj*16 + l15;
        float v = acc[mi][nj][j] + bias[col];
        if constexpr (EPI==0){ v += extra[(size_t)(row>>10)*N + col]; outb[(size_t)row*N+col] = f2bf(v); }
        else if constexpr (EPI==1){ v += extra[(size_t)row*N + col]; outf[(size_t)row*N+col] = v; }
        else { v = 0.5f*v*(1.f+erff(v*0.70710678118f)); outb[(size_t)row*N+col] = f2bf(v); }
      }
}

// ---------------- fused rel-position attention v4: 8 waves/WG, 3 WG/CU, swizzled P ----------------
// 512 threads; wave w: phase1 et in [w*8, w*8+8), phase2 kv in [w*128, (w+1)*128).
__global__ __launch_bounds__(512,6) void attn4(
    const ushort* __restrict__ qkv, const ushort* __restrict__ Er,
    const ushort* __restrict__ Vt, ushort* __restrict__ out)
{
  const int bid0 = blockIdx.x;
  const int bid = ((bid0 & 7) << 9) | (bid0 >> 3);   // 8 heads' worth of WGs per XCD
  const int rt = bid & 63, h = (bid>>6)&15, b = bid>>10;
  const int bh = b*16 + h;
  const int r0 = rt*16;
  const int tid = threadIdx.x, w = tid>>6, lane = tid&63;
  const int l15 = lane&15, l4 = lane>>4;

  __shared__ ushort RRF[17568];                      // 17 rows, flat stride 1033, skew-ready
  __shared__ __align__(16) char shpa[8*2048];        // per-wave 16x64 bf16, XOR-swizzled
  __shared__ float mlbuf[8][2][16];

  const size_t base = (size_t)b*1024*3072 + (size_t)h*64;
  const ushort* Qp = qkv + base;
  const ushort* Kp = qkv + base + 1024;
  const ushort* Vp = Vt + (size_t)bh*64*1024;
  char* shpb = shpa + w*2048;

  if (tid < 16) RRF[(tid+1)*1033] = 0;

  short8 qa[2], qb[2];
  const int q1 = min(r0 + 16 + l15, 1023);
  #pragma unroll
  for (int ks=0; ks<2; ++ks){
    qa[ks] = *(const short8*)(Qp + (size_t)(r0 + l15)*3072 + ks*32 + l4*8);
    qb[ks] = *(const short8*)(Qp + (size_t)q1*3072 + ks*32 + l4*8);
  }

  // Phase 1: rel rows r0..r0+16 into RRF (wave w: 8 et-tiles)
  #pragma unroll
  for (int t=0; t<8; ++t){
    const int et = w*8 + t;
    f32x4 a0 = {0.f,0.f,0.f,0.f}, a1 = {0.f,0.f,0.f,0.f};
    #pragma unroll
    for (int ks=0; ks<2; ++ks){
      short8 bfr = *(const short8*)(Er + (size_t)(et*16 + l15)*64 + ks*32 + l4*8);
      a0 = __builtin_amdgcn_mfma_f32_16x16x32_bf16(qa[ks], bfr, a0, 0,0,0);
      a1 = __builtin_amdgcn_mfma_f32_16x16x32_bf16(qb[ks], bfr, a1, 0,0,0);
    }
    const int e = et*16 + l15;
    #pragma unroll
    for (int j=0;j<4;j++) RRF[(l4*4+j)*1033 + 1 + e] = f2bf(a0[j]);
    if (l4 == 0) RRF[16*1033 + 1 + e] = f2bf(a1[0]);
  }
  __syncthreads();

  float m = -1e30f, lsum = 0.f;
  f32x4 Oacc[4];
  #pragma unroll
  for (int n2=0;n2<4;n2++){ Oacc[n2][0]=0.f; Oacc[n2][1]=0.f; Oacc[n2][2]=0.f; Oacc[n2][3]=0.f; }
  const int dl = 4*l4 - l15;
  const int rbase = l15*1033;
  const int swz = (l15&7)<<4;

  // Phase 2: online softmax over this wave's 2 kv-tiles; no barriers
  #pragma unroll
  for (int t=0;t<2;++t){
    const int c0 = w*128 + t*64;
    // skew reads first (latency hides under QK MFMAs)
    ushort skr[16];
    #pragma unroll
    for (int f=0;f<4;f++)
      #pragma unroll
      for (int j=0;j<4;j++){
        int d = (c0 + f*16 + j - r0) + dl;
        int off = (d<=0) ? (1024+d) : (1032+d);
        skr[f*4+j] = RRF[rbase + off];
      }
    f32x4 S[4];
    #pragma unroll
    for (int f=0;f<4;f++){
      short8 k0 = *(const short8*)(Kp + (size_t)(c0 + f*16 + l15)*3072 + l4*8);
      short8 k1 = *(const short8*)(Kp + (size_t)(c0 + f*16 + l15)*3072 + 32 + l4*8);
      S[f][0]=0.f; S[f][1]=0.f; S[f][2]=0.f; S[f][3]=0.f;
      S[f] = __builtin_amdgcn_mfma_f32_16x16x32_bf16(k0, qa[0], S[f], 0,0,0);
      S[f] = __builtin_amdgcn_mfma_f32_16x16x32_bf16(k1, qa[1], S[f], 0,0,0);
    }
    float tmax = -3e30f;
    #pragma unroll
    for (int f=0;f<4;f++)
      #pragma unroll
      for (int j=0;j<4;j++){
        float v = fmaf(S[f][j], 0.125f, bf2f(skr[f*4+j]));
        S[f][j] = v;
        tmax = fmaxf(tmax, v);
      }
    tmax = fmaxf(tmax, __shfl_xor(tmax, 16, 64));
    tmax = fmaxf(tmax, __shfl_xor(tmax, 32, 64));
    const float mn = fmaxf(m, tmax);
    const float scl = __expf(m - mn);
    m = mn;
    float tsum = 0.f;
    #pragma unroll
    for (int f=0;f<4;f++){
      float p0 = __expf(S[f][0]-m), p1 = __expf(S[f][1]-m), p2 = __expf(S[f][2]-m), p3 = __expf(S[f][3]-m);
      tsum += (p0+p1)+(p2+p3);
      ushort4 pw = make_ushort4(f2bf(p0), f2bf(p1), f2bf(p2), f2bf(p3));
      *(ushort4*)(shpb + (((l15<<7) + (f<<5) + (l4<<3)) ^ swz)) = pw;
    }
    tsum += __shfl_xor(tsum, 16, 64);
    tsum += __shfl_xor(tsum, 32, 64);
    lsum = lsum*scl + tsum;
    #pragma unroll
    for (int n2=0;n2<4;n2++)
      #pragma unroll
      for (int j=0;j<4;j++) Oacc[n2][j] *= scl;
    #pragma unroll
    for (int ks=0; ks<2; ++ks){
      short8 pb = *(const short8*)(shpb + (((l15<<7) + (ks<<6) + (l4<<4)) ^ swz));
      #pragma unroll
      for (int n2=0; n2<4; ++n2){
        short8 va = *(const short8*)(Vp + (size_t)(n2*16 + l15)*1024 + c0 + ks*32 + l4*8);
        Oacc[n2] = __builtin_amdgcn_mfma_f32_16x16x32_bf16(va, pb, Oacc[n2], 0,0,0);
      }
    }
  }

  // Phase 3: per-wave partials into own shp region, then 8-way merge
  #pragma unroll
  for (int n2=0;n2<4;n2++){
    ushort4 ow = make_ushort4(f2bf(Oacc[n2][0]), f2bf(Oacc[n2][1]), f2bf(Oacc[n2][2]), f2bf(Oacc[n2][3]));
    *(ushort4*)(shpb + (((l15<<7) + (n2<<5) + (l4<<3)) ^ swz)) = ow;
  }
  if (l4 == 0){ mlbuf[w][0][l15] = m; mlbuf[w][1][l15] = lsum; }
  __syncthreads();
  if (tid < 256){
    const int row = tid>>4, hb = tid&15;
    float M2 = mlbuf[0][0][row];
    #pragma unroll
    for (int w2=1;w2<8;w2++) M2 = fmaxf(M2, mlbuf[w2][0][row]);
    float den = 0.f, num[4] = {0.f,0.f,0.f,0.f};
    #pragma unroll
    for (int w2=0;w2<8;w2++){
      float e = __expf(mlbuf[w2][0][row] - M2);
      den += mlbuf[w2][1][row]*e;
      ushort4 ov = *(const ushort4*)(shpa + w2*2048 + (((row<<7) + (hb<<3)) ^ ((row&7)<<4)));
      num[0] += bf2f(ov.x)*e; num[1] += bf2f(ov.y)*e; num[2] += bf2f(ov.z)*e; num[3] += bf2f(ov.w)*e;
    }
    float inv = 1.f/den;
    ushort4 u;
    u.x = f2bf(num[0]*inv); u.y = f2bf(num[1]*inv); u.z = f2bf(num[2]*inv); u.w = f2bf(num[3]*inv);
    *(ushort4*)&out[((size_t)(b*1024 + r0 + row))*1024 + h*64 + hb*4] = u;
  }
}

extern "C" void kernel_launch(void* const* d_in, const int* in_sizes, int n_in,
                              void* d_out, int out_size, void* d_ws, size_t ws_size,
                              hipStream_t stream)
{
  const float* x    = (const float*)d_in[0];
  const float* t    = (const float*)d_in[1];
  const float* ln1g = (const float*)d_in[2];
  const float* ln1b = (const float*)d_in[3];
  const float* qkvw = (const float*)d_in[4];
  const float* qkvb = (const float*)d_in[5];
  const float* timew= (const float*)d_in[6];
  const float* timeb= (const float*)d_in[7];
  const float* outw = (const float*)d_in[8];
  const float* outbv= (const float*)d_in[9];
  const float* Er   = (const float*)d_in[10];
  const float* ln2g = (const float*)d_in[11];
  const float* ln2b = (const float*)d_in[12];
  const float* ff1w = (const float*)d_in[13];
  const float* ff1b = (const float*)d_in[14];
  const float* ff2w = (const float*)d_in[15];
  const float* ff2b = (const float*)d_in[16];
  float* o = (float*)d_out;

  char* ws = (char*)d_ws;
  ushort* qkvw_t = (ushort*)(ws);              // [3072][1024]
  ushort* outw_t = (ushort*)(ws + 6291456);    // [1024][1024]
  ushort* ff1w_t = (ushort*)(ws + 8388608);    // [4096][1024]
  ushort* ff2w_t = (ushort*)(ws + 16777216);   // [1024][4096]
  ushort* er_b   = (ushort*)(ws + 25165824);   // [1024][64]
  float*  tq     = (float*) (ws + 25296896);   // [4][3072]
  ushort* bufA   = (ushort*)(ws + 25346048);   // 4096x1024 bf16: xn -> attn_out -> h
  ushort* vt     = (ushort*)(ws + 33734656);   // [64*64][1024] bf16 V-transposed
  ushort* bufB   = (ushort*)(ws + 42123264);   // qkv 4096x3072 / ff1o 4096x4096

  wt_cvt<<<dim3(48,16),256,0,stream>>>(qkvw, qkvw_t, 1024, 3072);
  wt_cvt<<<dim3(16,16),256,0,stream>>>(outw, outw_t, 1024, 1024);
  wt_cvt<<<dim3(64,16),256,0,stream>>>(ff1w, ff1w_t, 1024, 4096);
  wt_cvt<<<dim3(16,64),256,0,stream>>>(ff2w, ff2w_t, 4096, 1024);
  cvt_f2b<<<256,256,0,stream>>>(Er, er_b, 65536);

  ln_rows<<<4096,256,0,stream>>>(x, ln1g, ln1b, bufA);
  tq_gemm2<<<48,256,0,stream>>>(t, timew, timeb, tq);
  gemm3<0><<<768,256,0,stream>>>(bufA, qkvw_t, qkvb, tq, bufB, nullptr, 4096,3072,1024, 24);
  vt_k<<<dim3(16,64),256,0,stream>>>(bufB, vt);
  attn4<<<4096,512,0,stream>>>(bufB, er_b, vt, bufA);
  gemm3<1><<<256,256,0,stream>>>(bufA, outw_t, outbv, x, nullptr, o, 4096,1024,1024, 8);
  ln_rows<<<4096,256,0,stream>>>(o, ln2g, ln2b, bufA);
  gemm3<2><<<1024,256,0,stream>>>(bufA, ff1w_t, ff1b, nullptr, bufB, nullptr, 4096,4096,1024, 32);
  gemm3<1><<<256,256,0,stream>>>(bufB, ff2w_t, ff2b, o, nullptr, o, 4096,1024,4096, 8);
}

// Round 5
// 445.102 us; speedup vs baseline: 1.0543x; 1.0543x over previous
//
#include <hip/hip_runtime.h>
#include <hip/hip_bf16.h>

typedef __attribute__((ext_vector_type(8))) short short8;
typedef __attribute__((ext_vector_type(4))) float f32x4;

#define DEV __device__ __forceinline__

DEV float bf2f(ushort u){ union { float f; unsigned int i; } x; x.i = ((unsigned int)u)<<16; return x.f; }
DEV ushort f2bf(float f){ union { float fl; unsigned int i; } x; x.fl = f; unsigned int r = x.i + 0x7fffu + ((x.i>>16)&1u); return (ushort)(r>>16); }

DEV void gl2lds16(const ushort* g, ushort* l){
  __builtin_amdgcn_global_load_lds((const __attribute__((address_space(1))) void*)g,
                                   (__attribute__((address_space(3))) void*)l, 16, 0, 0);
}

// ---------------- fp32 -> bf16 convert (Er only) ----------------
__global__ void cvt_f2b(const float* __restrict__ in, ushort* __restrict__ out, int n){
  int i = blockIdx.x*blockDim.x + threadIdx.x;
  int stride = gridDim.x*blockDim.x;
  for (; i < n; i += stride) out[i] = f2bf(in[i]);
}

// ---------------- fp32 [K][N] -> bf16 [N][K+pad] tiled transpose ----------------
__global__ __launch_bounds__(256) void wt_cvt(const float* __restrict__ in, ushort* __restrict__ out,
                                              int K, int N, int ldk){
  const int n0 = blockIdx.x*64, k0 = blockIdx.y*64;
  __shared__ float T[64][65];
  const int tid = threadIdx.x;
  const int r = tid>>4, c = (tid&15)*4;
  #pragma unroll
  for (int p=0;p<4;p++){
    float4 v = *(const float4*)&in[(size_t)(k0 + p*16 + r)*N + n0 + c];
    T[p*16+r][c+0]=v.x; T[p*16+r][c+1]=v.y; T[p*16+r][c+2]=v.z; T[p*16+r][c+3]=v.w;
  }
  __syncthreads();
  #pragma unroll
  for (int p=0;p<4;p++){
    int n = p*16 + r;
    ushort u0 = f2bf(T[c+0][n]), u1 = f2bf(T[c+1][n]), u2 = f2bf(T[c+2][n]), u3 = f2bf(T[c+3][n]);
    ushort4 u = make_ushort4(u0,u1,u2,u3);
    *(ushort4*)&out[(size_t)(n0+n)*ldk + k0 + c] = u;
  }
}

// ---------------- V transpose: qkv V-part [n][hd] -> Vt [(bh*64+hd)][n], padded strides --------
__global__ __launch_bounds__(256) void vt_k(const ushort* __restrict__ qkv, ushort* __restrict__ vt){
  const int bh = blockIdx.y; const int b = bh>>4, h = bh&15;
  const int n0 = blockIdx.x*64;
  __shared__ ushort T[64][66];
  const int tid = threadIdx.x;
  const int r = tid>>3, c8 = (tid&7)*8;
  #pragma unroll
  for (int p=0;p<2;p++){
    int row = p*32 + r;
    short8 v = *(const short8*)&qkv[(size_t)(b*1024 + n0 + row)*3200 + 2048 + h*64 + c8];
    #pragma unroll
    for (int i=0;i<8;i++) T[row][c8+i] = ((ushort*)&v)[i];
  }
  __syncthreads();
  #pragma unroll
  for (int p=0;p<2;p++){
    int d = p*32 + r;
    union { ushort u[8]; short8 v; } o;
    #pragma unroll
    for (int i=0;i<8;i++) o.u[i] = T[c8+i][d];
    *(short8*)&vt[(size_t)(bh*64 + d)*1152 + n0 + c8] = o.v;
  }
}

// ---------------- LayerNorm over C=1024, one row per block; padded bf16 out ----------------
__global__ __launch_bounds__(256) void ln_rows(const float* __restrict__ in,
                                               const float* __restrict__ g,
                                               const float* __restrict__ bta,
                                               ushort* __restrict__ out, int ldo){
  int row = blockIdx.x; int tid = threadIdx.x;
  const float* x = in + (size_t)row*1024;
  float v[4]; float s = 0.f;
  #pragma unroll
  for (int i=0;i<4;i++){ v[i] = x[tid + 256*i]; s += v[i]; }
  __shared__ float rbuf[256];
  rbuf[tid] = s; __syncthreads();
  for (int off=128; off>0; off>>=1){ if (tid<off) rbuf[tid]+=rbuf[tid+off]; __syncthreads(); }
  float mean = rbuf[0] * (1.f/1024.f);
  __syncthreads();
  float s2 = 0.f;
  #pragma unroll
  for (int i=0;i<4;i++){ float d=v[i]-mean; s2 += d*d; }
  rbuf[tid] = s2; __syncthreads();
  for (int off=128; off>0; off>>=1){ if (tid<off) rbuf[tid]+=rbuf[tid+off]; __syncthreads(); }
  float var = rbuf[0] * (1.f/1024.f);
  float rstd = rsqrtf(var + 1e-5f);
  #pragma unroll
  for (int i=0;i<4;i++){ int c = tid+256*i; out[(size_t)row*ldo+c] = f2bf((v[i]-mean)*rstd*g[c]+bta[c]); }
}

// ---------------- time-embedding GEMM ----------------
__global__ __launch_bounds__(256) void tq_gemm2(const float* __restrict__ t, const float* __restrict__ tw,
                                                const float* __restrict__ tb, float* __restrict__ tq){
  const int tid = threadIdx.x;
  const int j = blockIdx.x*64 + (tid & 63);
  const int sl = tid >> 6;
  float acc[4] = {0.f,0.f,0.f,0.f};
  for (int k = sl*64; k < sl*64+64; ++k){
    float wv = tw[(size_t)k*3072 + j];
    #pragma unroll
    for (int b=0;b<4;b++) acc[b] = fmaf(t[b*256+k], wv, acc[b]);
  }
  __shared__ float red[4][4][64];
  #pragma unroll
  for (int b=0;b<4;b++) red[sl][b][tid&63] = acc[b];
  __syncthreads();
  if (sl == 0){
    #pragma unroll
    for (int b=0;b<4;b++)
      tq[b*3072 + j] = red[0][b][tid&63] + red[1][b][tid&63] + red[2][b][tid&63] + red[3][b][tid&63] + tb[j];
  }
}

// ---------------- m97-style 128xTN GEMM: BK=32, linear LDS, global_load_lds, XCD swizzle -------
// EPI 0: outb = acc + bias[col] + extra[(row>>10)*lde + col]   (QKV + time-bias)
// EPI 1: outf = acc + bias[col] + extra[row*lde + col]         (residual add, fp32 out)
// EPI 2: outb = gelu(acc + bias[col])                          (FF1)
template<int EPI, int TN>
__global__ __launch_bounds__(256) void gemm3(
    const ushort* __restrict__ A, const ushort* __restrict__ Bt,
    const float* __restrict__ bias, const float* __restrict__ extra,
    ushort* __restrict__ outb, float* __restrict__ outf,
    int K, int lda, int ldb, int ldo, int lde, int nbx)
{
  constexpr int NJ = TN/32;
  __shared__ __align__(16) ushort Al[128*32];
  __shared__ __align__(16) ushort Bl[TN*32];
  const int nwg = gridDim.x, cpx = nwg >> 3;
  const int bid = blockIdx.x;
  const int swz = (bid & 7)*cpx + (bid >> 3);
  const int m0 = (swz / nbx)*128, n0 = (swz % nbx)*TN;
  const int tid = threadIdx.x, lane = tid & 63, wid = tid >> 6;
  const int wm = (wid&1)*64, wn = (wid>>1)*(TN/2);
  const int l15 = lane&15, l4 = lane>>4;
  f32x4 acc[4][NJ];
  #pragma unroll
  for (int i=0;i<4;i++)
    #pragma unroll
    for (int jx=0;jx<NJ;jx++){ acc[i][jx][0]=0.f; acc[i][jx][1]=0.f; acc[i][jx][2]=0.f; acc[i][jx][3]=0.f; }
  const int chA0 = tid, chA1 = tid + 256;
  const ushort* a0p = A + (size_t)(m0 + (chA0>>2))*lda + (chA0&3)*8;
  const ushort* a1p = A + (size_t)(m0 + (chA1>>2))*lda + (chA1&3)*8;
  ushort* la0 = &Al[chA0*8]; ushort* la1 = &Al[chA1*8];
  const ushort* b0p = Bt + (size_t)(n0 + (tid>>2))*ldb + (tid&3)*8;
  ushort* lb0 = &Bl[tid*8];
  const ushort* b1p = nullptr; ushort* lb1 = nullptr;
  if constexpr (TN==128){
    b1p = Bt + (size_t)(n0 + ((tid+256)>>2))*ldb + (tid&3)*8;
    lb1 = &Bl[(tid+256)*8];
  }
  for (int k0=0; k0<K; k0+=32){
    __syncthreads();
    gl2lds16(a0p + k0, la0);
    gl2lds16(a1p + k0, la1);
    gl2lds16(b0p + k0, lb0);
    if constexpr (TN==128) gl2lds16(b1p + k0, lb1);
    __syncthreads();
    short8 af[4], bfr[NJ];
    #pragma unroll
    for (int mi=0;mi<4;mi++) af[mi]  = *(const short8*)&Al[(wm + mi*16 + l15)*32 + l4*8];
    #pragma unroll
    for (int nj=0;nj<NJ;nj++) bfr[nj] = *(const short8*)&Bl[(wn + nj*16 + l15)*32 + l4*8];
    #pragma unroll
    for (int mi=0;mi<4;mi++)
      #pragma unroll
      for (int nj=0;nj<NJ;nj++)
        acc[mi][nj] = __builtin_amdgcn_mfma_f32_16x16x32_bf16(af[mi], bfr[nj], acc[mi][nj], 0,0,0);
  }
  #pragma unroll
  for (int mi=0;mi<4;mi++)
    #pragma unroll
    for (int nj=0;nj<NJ;nj++)
      #pragma unroll
      for (int j=0;j<4;j++){
        int row = m0 + wm + mi*16 + l4*4 + j;
        int col = n0 + wn + nj*16 + l15;
        float v = acc[mi][nj][j] + bias[col];
        if constexpr (EPI==0){ v += extra[(size_t)(row>>10)*lde + col]; outb[(size_t)row*ldo+col] = f2bf(v); }
        else if constexpr (EPI==1){ v += extra[(size_t)row*lde + col]; outf[(size_t)row*ldo+col] = v; }
        else { v = 0.5f*v*(1.f+erff(v*0.70710678118f)); outb[(size_t)row*ldo+col] = f2bf(v); }
      }
}

// ---------------- fused rel-position attention v5: padded strides + hoisted skew + setprio -----
// grid 4096; 16 q-rows per WG, 4 waves split 16 kv-tiles (4 each). qkv stride 3200, Vt/out 1152.
__global__ __launch_bounds__(256,3) void attn5(
    const ushort* __restrict__ qkv, const ushort* __restrict__ Er,
    const ushort* __restrict__ Vt, ushort* __restrict__ out)
{
  const int bid0 = blockIdx.x;
  const int bid = ((bid0 & 7) << 9) | (bid0 >> 3);   // 8 heads' worth of WGs per XCD
  const int rt = bid & 63, h = (bid>>6)&15, b = bid>>10;
  const int bh = b*16 + h;
  const int r0 = rt*16;
  const int tid = threadIdx.x, w = tid>>6, lane = tid&63;
  const int l15 = lane&15, l4 = lane>>4;

  __shared__ ushort RRF[17568];                      // 17 rows, flat stride 1033, skew-ready
  __shared__ __align__(16) ushort shp[4][16][88];    // P^T then O^T partials
  __shared__ float mlbuf[4][2][16];

  const size_t base = (size_t)b*1024*3200 + (size_t)h*64;
  const ushort* Qp = qkv + base;
  const ushort* Kp = qkv + base + 1024;
  const ushort* Vp = Vt + (size_t)bh*64*1152;

  if (tid < 16) RRF[(tid+1)*1033] = 0;

  short8 qa[2], qb[2];
  const int q1 = min(r0 + 16 + l15, 1023);
  #pragma unroll
  for (int ks=0; ks<2; ++ks){
    qa[ks] = *(const short8*)(Qp + (size_t)(r0 + l15)*3200 + ks*32 + l4*8);
    qb[ks] = *(const short8*)(Qp + (size_t)q1*3200 + ks*32 + l4*8);
  }

  // Phase 1: rel rows r0..r0+16 into RRF; Er loads software-pipelined one tile ahead
  short8 e0 = *(const short8*)(Er + (size_t)(w*256 + l15)*64 + l4*8);
  short8 e1 = *(const short8*)(Er + (size_t)(w*256 + l15)*64 + 32 + l4*8);
  for (int t=0; t<16; ++t){
    const int et = w*16 + t;
    short8 c0v = e0, c1v = e1;
    if (t < 15){
      e0 = *(const short8*)(Er + (size_t)((et+1)*16 + l15)*64 + l4*8);
      e1 = *(const short8*)(Er + (size_t)((et+1)*16 + l15)*64 + 32 + l4*8);
    }
    f32x4 a0 = {0.f,0.f,0.f,0.f}, a1 = {0.f,0.f,0.f,0.f};
    __builtin_amdgcn_s_setprio(1);
    a0 = __builtin_amdgcn_mfma_f32_16x16x32_bf16(qa[0], c0v, a0, 0,0,0);
    a1 = __builtin_amdgcn_mfma_f32_16x16x32_bf16(qb[0], c0v, a1, 0,0,0);
    a0 = __builtin_amdgcn_mfma_f32_16x16x32_bf16(qa[1], c1v, a0, 0,0,0);
    a1 = __builtin_amdgcn_mfma_f32_16x16x32_bf16(qb[1], c1v, a1, 0,0,0);
    __builtin_amdgcn_s_setprio(0);
    const int e = et*16 + l15;
    #pragma unroll
    for (int j=0;j<4;j++) RRF[(l4*4+j)*1033 + 1 + e] = f2bf(a0[j]);
    if (l4 == 0) RRF[16*1033 + 1 + e] = f2bf(a1[0]);
  }
  __syncthreads();

  float m = -1e30f, lsum = 0.f;
  f32x4 Oacc[4];
  #pragma unroll
  for (int n2=0;n2<4;n2++){ Oacc[n2][0]=0.f; Oacc[n2][1]=0.f; Oacc[n2][2]=0.f; Oacc[n2][3]=0.f; }
  const int dl = 4*l4 - l15;
  const int rbase = l15*1033;
  const int c0base = w*256;

  // Phase 2: online softmax with K double-buffer; no barriers in loop
  short8 ka[2][4][2];
  #pragma unroll
  for (int f=0;f<4;f++)
    #pragma unroll
    for (int ks=0;ks<2;ks++)
      ka[0][f][ks] = *(const short8*)(Kp + (size_t)(c0base + f*16 + l15)*3200 + ks*32 + l4*8);

  #pragma unroll
  for (int t=0;t<4;++t){
    const int cur = t&1;
    const int c0 = c0base + t*64;
    // hoisted skew reads: latency hides under the QK MFMAs below
    float skf[16];
    #pragma unroll
    for (int f=0;f<4;f++)
      #pragma unroll
      for (int j=0;j<4;j++){
        int d = (c0 + f*16 + j - r0) + dl;
        int off = (d<=0) ? (1024+d) : (1032+d);
        skf[f*4+j] = bf2f(RRF[rbase + off]);
      }
    f32x4 S[4];
    __builtin_amdgcn_s_setprio(1);
    #pragma unroll
    for (int f=0;f<4;f++){
      S[f][0]=0.f; S[f][1]=0.f; S[f][2]=0.f; S[f][3]=0.f;
      #pragma unroll
      for (int ks=0;ks<2;ks++)
        S[f] = __builtin_amdgcn_mfma_f32_16x16x32_bf16(ka[cur][f][ks], qa[ks], S[f], 0,0,0);
    }
    __builtin_amdgcn_s_setprio(0);
    if (t < 3){
      const int c2 = c0 + 64;
      #pragma unroll
      for (int f=0;f<4;f++)
        #pragma unroll
        for (int ks=0;ks<2;ks++)
          ka[cur^1][f][ks] = *(const short8*)(Kp + (size_t)(c2 + f*16 + l15)*3200 + ks*32 + l4*8);
    }
    short8 va[2][4];
    #pragma unroll
    for (int ks=0;ks<2;ks++)
      #pragma unroll
      for (int n2=0;n2<4;n2++)
        va[ks][n2] = *(const short8*)(Vp + (size_t)(n2*16 + l15)*1152 + c0 + ks*32 + l4*8);
    // scale + skew; per-f tree max then combine (depth ~4 instead of 16)
    float tm[4];
    #pragma unroll
    for (int f=0;f<4;f++){
      float v0 = fmaf(S[f][0], 0.125f, skf[f*4+0]);
      float v1 = fmaf(S[f][1], 0.125f, skf[f*4+1]);
      float v2 = fmaf(S[f][2], 0.125f, skf[f*4+2]);
      float v3 = fmaf(S[f][3], 0.125f, skf[f*4+3]);
      S[f][0]=v0; S[f][1]=v1; S[f][2]=v2; S[f][3]=v3;
      tm[f] = fmaxf(fmaxf(v0,v1), fmaxf(v2,v3));
    }
    float tmax = fmaxf(fmaxf(tm[0],tm[1]), fmaxf(tm[2],tm[3]));
    tmax = fmaxf(tmax, __shfl_xor(tmax, 16, 64));
    tmax = fmaxf(tmax, __shfl_xor(tmax, 32, 64));
    const float mn = fmaxf(m, tmax);
    const float scl = __expf(m - mn);
    m = mn;
    float tsum = 0.f;
    #pragma unroll
    for (int f=0;f<4;f++){
      float p0 = __expf(S[f][0]-m), p1 = __expf(S[f][1]-m), p2 = __expf(S[f][2]-m), p3 = __expf(S[f][3]-m);
      tsum += (p0+p1)+(p2+p3);
      ushort4 pw = make_ushort4(f2bf(p0), f2bf(p1), f2bf(p2), f2bf(p3));
      *(ushort4*)&shp[w][l15][f*16 + l4*4] = pw;
    }
    tsum += __shfl_xor(tsum, 16, 64);
    tsum += __shfl_xor(tsum, 32, 64);
    lsum = lsum*scl + tsum;
    #pragma unroll
    for (int n2=0;n2<4;n2++)
      #pragma unroll
      for (int j=0;j<4;j++) Oacc[n2][j] *= scl;
    __builtin_amdgcn_s_setprio(1);
    #pragma unroll
    for (int ks=0; ks<2; ++ks){
      short8 pb = *(const short8*)&shp[w][l15][ks*32 + l4*8];
      #pragma unroll
      for (int n2=0; n2<4; ++n2)
        Oacc[n2] = __builtin_amdgcn_mfma_f32_16x16x32_bf16(va[ks][n2], pb, Oacc[n2], 0,0,0);
    }
    __builtin_amdgcn_s_setprio(0);
  }

  // Phase 3: per-wave partials into own shp region, then merge
  #pragma unroll
  for (int n2=0;n2<4;n2++){
    ushort4 ow = make_ushort4(f2bf(Oacc[n2][0]), f2bf(Oacc[n2][1]), f2bf(Oacc[n2][2]), f2bf(Oacc[n2][3]));
    *(ushort4*)&shp[w][l15][n2*16 + l4*4] = ow;
  }
  if (l4 == 0){ mlbuf[w][0][l15] = m; mlbuf[w][1][l15] = lsum; }
  __syncthreads();
  {
    const int row = tid>>4, hb = (tid&15)*4;
    float M2 = mlbuf[0][0][row];
    #pragma unroll
    for (int w2=1;w2<4;w2++) M2 = fmaxf(M2, mlbuf[w2][0][row]);
    float den = 0.f, num[4] = {0.f,0.f,0.f,0.f};
    #pragma unroll
    for (int w2=0;w2<4;w2++){
      float e = __expf(mlbuf[w2][0][row] - M2);
      den += mlbuf[w2][1][row]*e;
      ushort4 ov = *(const ushort4*)&shp[w2][row][hb];
      num[0] += bf2f(ov.x)*e; num[1] += bf2f(ov.y)*e; num[2] += bf2f(ov.z)*e; num[3] += bf2f(ov.w)*e;
    }
    float inv = 1.f/den;
    ushort4 u;
    u.x = f2bf(num[0]*inv); u.y = f2bf(num[1]*inv); u.z = f2bf(num[2]*inv); u.w = f2bf(num[3]*inv);
    *(ushort4*)&out[((size_t)(b*1024 + r0 + row))*1152 + h*64 + hb] = u;
  }
}

extern "C" void kernel_launch(void* const* d_in, const int* in_sizes, int n_in,
                              void* d_out, int out_size, void* d_ws, size_t ws_size,
                              hipStream_t stream)
{
  const float* x    = (const float*)d_in[0];
  const float* t    = (const float*)d_in[1];
  const float* ln1g = (const float*)d_in[2];
  const float* ln1b = (const float*)d_in[3];
  const float* qkvw = (const float*)d_in[4];
  const float* qkvb = (const float*)d_in[5];
  const float* timew= (const float*)d_in[6];
  const float* timeb= (const float*)d_in[7];
  const float* outw = (const float*)d_in[8];
  const float* outbv= (const float*)d_in[9];
  const float* Er   = (const float*)d_in[10];
  const float* ln2g = (const float*)d_in[11];
  const float* ln2b = (const float*)d_in[12];
  const float* ff1w = (const float*)d_in[13];
  const float* ff1b = (const float*)d_in[14];
  const float* ff2w = (const float*)d_in[15];
  const float* ff2b = (const float*)d_in[16];
  float* o = (float*)d_out;

  // Padded row strides (odd multiples of 256B) to avoid L2 channel camping:
  // 1024 -> 1152, 3072 -> 3200, 4096 -> 4224 (ushort units)
  char* ws = (char*)d_ws;
  ushort* qkvw_t = (ushort*)(ws);              // [3072][1152]
  ushort* outw_t = (ushort*)(ws + 7077888);    // [1024][1152]
  ushort* ff1w_t = (ushort*)(ws + 9437184);    // [4096][1152]
  ushort* ff2w_t = (ushort*)(ws + 18874368);   // [1024][4224]
  ushort* er_b   = (ushort*)(ws + 27525120);   // [1024][64]
  float*  tq     = (float*) (ws + 27656192);   // [4][3072]
  ushort* bufA   = (ushort*)(ws + 27705344);   // [4096][1152]: xn -> attn_out -> h
  ushort* vt     = (ushort*)(ws + 37142528);   // [4096][1152]: V transposed
  ushort* bufB   = (ushort*)(ws + 46579712);   // [4096][4224]: qkv (stride 3200) / ff1o (4224)
  // total ws usage: 81,182,720 bytes

  wt_cvt<<<dim3(48,16),256,0,stream>>>(qkvw, qkvw_t, 1024, 3072, 1152);
  wt_cvt<<<dim3(16,16),256,0,stream>>>(outw, outw_t, 1024, 1024, 1152);
  wt_cvt<<<dim3(64,16),256,0,stream>>>(ff1w, ff1w_t, 1024, 4096, 1152);
  wt_cvt<<<dim3(16,64),256,0,stream>>>(ff2w, ff2w_t, 4096, 1024, 4224);
  cvt_f2b<<<256,256,0,stream>>>(Er, er_b, 65536);

  ln_rows<<<4096,256,0,stream>>>(x, ln1g, ln1b, bufA, 1152);
  tq_gemm2<<<48,256,0,stream>>>(t, timew, timeb, tq);
  gemm3<0,128><<<768,256,0,stream>>>(bufA, qkvw_t, qkvb, tq, bufB, nullptr,
                                     1024, 1152, 1152, 3200, 3072, 24);
  vt_k<<<dim3(16,64),256,0,stream>>>(bufB, vt);
  attn5<<<4096,256,0,stream>>>(bufB, er_b, vt, bufA);
  gemm3<1,64><<<512,256,0,stream>>>(bufA, outw_t, outbv, x, nullptr, o,
                                    1024, 1152, 1152, 1024, 1024, 16);
  ln_rows<<<4096,256,0,stream>>>(o, ln2g, ln2b, bufA, 1152);
  gemm3<2,128><<<1024,256,0,stream>>>(bufA, ff1w_t, ff1b, nullptr, bufB, nullptr,
                                      1024, 1152, 1152, 4224, 0, 32);
  gemm3<1,64><<<512,256,0,stream>>>(bufB, ff2w_t, ff2b, o, nullptr, o,
                                    4096, 4224, 4224, 1024, 1024, 16);
}

// Round 6
// 429.251 us; speedup vs baseline: 1.0932x; 1.0369x over previous
//
#include <hip/hip_runtime.h>
#include <hip/hip_bf16.h>

typedef __attribute__((ext_vector_type(8))) short short8;
typedef __attribute__((ext_vector_type(4))) float f32x4;
typedef __attribute__((ext_vector_type(16))) float f32x16;

#define DEV __device__ __forceinline__

DEV float bf2f(ushort u){ union { float f; unsigned int i; } x; x.i = ((unsigned int)u)<<16; return x.f; }
DEV ushort f2bf(float f){ union { float fl; unsigned int i; } x; x.fl = f; unsigned int r = x.i + 0x7fffu + ((x.i>>16)&1u); return (ushort)(r>>16); }

DEV void gl2lds16(const ushort* g, ushort* l){
  __builtin_amdgcn_global_load_lds((const __attribute__((address_space(1))) void*)g,
                                   (__attribute__((address_space(3))) void*)l, 16, 0, 0);
}
DEV f32x16 mfma32(short8 a, short8 b, f32x16 c){
  return __builtin_amdgcn_mfma_f32_32x32x16_bf16(a, b, c, 0, 0, 0);
}
DEV uint cvtpk(float lo, float hi){
  uint r; asm("v_cvt_pk_bf16_f32 %0, %1, %2" : "=v"(r) : "v"(lo), "v"(hi));
  return r;
}

// ---------------- fp32 -> bf16 convert (Er only) ----------------
__global__ void cvt_f2b(const float* __restrict__ in, ushort* __restrict__ out, int n){
  int i = blockIdx.x*blockDim.x + threadIdx.x;
  int stride = gridDim.x*blockDim.x;
  for (; i < n; i += stride) out[i] = f2bf(in[i]);
}

// ---------------- fp32 [K][N] -> bf16 [N][K+pad] tiled transpose ----------------
__global__ __launch_bounds__(256) void wt_cvt(const float* __restrict__ in, ushort* __restrict__ out,
                                              int K, int N, int ldk){
  const int n0 = blockIdx.x*64, k0 = blockIdx.y*64;
  __shared__ float T[64][65];
  const int tid = threadIdx.x;
  const int r = tid>>4, c = (tid&15)*4;
  #pragma unroll
  for (int p=0;p<4;p++){
    float4 v = *(const float4*)&in[(size_t)(k0 + p*16 + r)*N + n0 + c];
    T[p*16+r][c+0]=v.x; T[p*16+r][c+1]=v.y; T[p*16+r][c+2]=v.z; T[p*16+r][c+3]=v.w;
  }
  __syncthreads();
  #pragma unroll
  for (int p=0;p<4;p++){
    int n = p*16 + r;
    ushort u0 = f2bf(T[c+0][n]), u1 = f2bf(T[c+1][n]), u2 = f2bf(T[c+2][n]), u3 = f2bf(T[c+3][n]);
    ushort4 u = make_ushort4(u0,u1,u2,u3);
    *(ushort4*)&out[(size_t)(n0+n)*ldk + k0 + c] = u;
  }
}

// ---------------- V transpose: qkv V-part [n][hd] -> Vt [(bh*64+hd)][n] ----------------
__global__ __launch_bounds__(256) void vt_k(const ushort* __restrict__ qkv, ushort* __restrict__ vt){
  const int bh = blockIdx.y; const int b = bh>>4, h = bh&15;
  const int n0 = blockIdx.x*64;
  __shared__ ushort T[64][66];
  const int tid = threadIdx.x;
  const int r = tid>>3, c8 = (tid&7)*8;
  #pragma unroll
  for (int p=0;p<2;p++){
    int row = p*32 + r;
    short8 v = *(const short8*)&qkv[(size_t)(b*1024 + n0 + row)*3200 + 2048 + h*64 + c8];
    #pragma unroll
    for (int i=0;i<8;i++) T[row][c8+i] = ((ushort*)&v)[i];
  }
  __syncthreads();
  #pragma unroll
  for (int p=0;p<2;p++){
    int d = p*32 + r;
    union { ushort u[8]; short8 v; } o;
    #pragma unroll
    for (int i=0;i<8;i++) o.u[i] = T[c8+i][d];
    *(short8*)&vt[(size_t)(bh*64 + d)*1152 + n0 + c8] = o.v;
  }
}

// ---------------- LayerNorm over C=1024 ----------------
__global__ __launch_bounds__(256) void ln_rows(const float* __restrict__ in,
                                               const float* __restrict__ g,
                                               const float* __restrict__ bta,
                                               ushort* __restrict__ out, int ldo){
  int row = blockIdx.x; int tid = threadIdx.x;
  const float* x = in + (size_t)row*1024;
  float v[4]; float s = 0.f;
  #pragma unroll
  for (int i=0;i<4;i++){ v[i] = x[tid + 256*i]; s += v[i]; }
  __shared__ float rbuf[256];
  rbuf[tid] = s; __syncthreads();
  for (int off=128; off>0; off>>=1){ if (tid<off) rbuf[tid]+=rbuf[tid+off]; __syncthreads(); }
  float mean = rbuf[0] * (1.f/1024.f);
  __syncthreads();
  float s2 = 0.f;
  #pragma unroll
  for (int i=0;i<4;i++){ float d=v[i]-mean; s2 += d*d; }
  rbuf[tid] = s2; __syncthreads();
  for (int off=128; off>0; off>>=1){ if (tid<off) rbuf[tid]+=rbuf[tid+off]; __syncthreads(); }
  float var = rbuf[0] * (1.f/1024.f);
  float rstd = rsqrtf(var + 1e-5f);
  #pragma unroll
  for (int i=0;i<4;i++){ int c = tid+256*i; out[(size_t)row*ldo+c] = f2bf((v[i]-mean)*rstd*g[c]+bta[c]); }
}

// ---------------- time-embedding GEMM ----------------
__global__ __launch_bounds__(256) void tq_gemm2(const float* __restrict__ t, const float* __restrict__ tw,
                                                const float* __restrict__ tb, float* __restrict__ tq){
  const int tid = threadIdx.x;
  const int j = blockIdx.x*64 + (tid & 63);
  const int sl = tid >> 6;
  float acc[4] = {0.f,0.f,0.f,0.f};
  for (int k = sl*64; k < sl*64+64; ++k){
    float wv = tw[(size_t)k*3072 + j];
    #pragma unroll
    for (int b=0;b<4;b++) acc[b] = fmaf(t[b*256+k], wv, acc[b]);
  }
  __shared__ float red[4][4][64];
  #pragma unroll
  for (int b=0;b<4;b++) red[sl][b][tid&63] = acc[b];
  __syncthreads();
  if (sl == 0){
    #pragma unroll
    for (int b=0;b<4;b++)
      tq[b*3072 + j] = red[0][b][tid&63] + red[1][b][tid&63] + red[2][b][tid&63] + red[3][b][tid&63] + tb[j];
  }
}

// ---------------- m97-style 128xTN GEMM ----------------
template<int EPI, int TN>
__global__ __launch_bounds__(256) void gemm3(
    const ushort* __restrict__ A, const ushort* __restrict__ Bt,
    const float* __restrict__ bias, const float* __restrict__ extra,
    ushort* __restrict__ outb, float* __restrict__ outf,
    int K, int lda, int ldb, int ldo, int lde, int nbx)
{
  constexpr int NJ = TN/32;
  __shared__ __align__(16) ushort Al[128*32];
  __shared__ __align__(16) ushort Bl[TN*32];
  const int nwg = gridDim.x, cpx = nwg >> 3;
  const int bid = blockIdx.x;
  const int swz = (bid & 7)*cpx + (bid >> 3);
  const int m0 = (swz / nbx)*128, n0 = (swz % nbx)*TN;
  const int tid = threadIdx.x, lane = tid & 63, wid = tid >> 6;
  const int wm = (wid&1)*64, wn = (wid>>1)*(TN/2);
  const int l15 = lane&15, l4 = lane>>4;
  f32x4 acc[4][NJ];
  #pragma unroll
  for (int i=0;i<4;i++)
    #pragma unroll
    for (int jx=0;jx<NJ;jx++){ acc[i][jx][0]=0.f; acc[i][jx][1]=0.f; acc[i][jx][2]=0.f; acc[i][jx][3]=0.f; }
  const int chA0 = tid, chA1 = tid + 256;
  const ushort* a0p = A + (size_t)(m0 + (chA0>>2))*lda + (chA0&3)*8;
  const ushort* a1p = A + (size_t)(m0 + (chA1>>2))*lda + (chA1&3)*8;
  ushort* la0 = &Al[chA0*8]; ushort* la1 = &Al[chA1*8];
  const ushort* b0p = Bt + (size_t)(n0 + (tid>>2))*ldb + (tid&3)*8;
  ushort* lb0 = &Bl[tid*8];
  const ushort* b1p = nullptr; ushort* lb1 = nullptr;
  if constexpr (TN==128){
    b1p = Bt + (size_t)(n0 + ((tid+256)>>2))*ldb + (tid&3)*8;
    lb1 = &Bl[(tid+256)*8];
  }
  for (int k0=0; k0<K; k0+=32){
    __syncthreads();
    gl2lds16(a0p + k0, la0);
    gl2lds16(a1p + k0, la1);
    gl2lds16(b0p + k0, lb0);
    if constexpr (TN==128) gl2lds16(b1p + k0, lb1);
    __syncthreads();
    short8 af[4], bfr[NJ];
    #pragma unroll
    for (int mi=0;mi<4;mi++) af[mi]  = *(const short8*)&Al[(wm + mi*16 + l15)*32 + l4*8];
    #pragma unroll
    for (int nj=0;nj<NJ;nj++) bfr[nj] = *(const short8*)&Bl[(wn + nj*16 + l15)*32 + l4*8];
    #pragma unroll
    for (int mi=0;mi<4;mi++)
      #pragma unroll
      for (int nj=0;nj<NJ;nj++)
        acc[mi][nj] = __builtin_amdgcn_mfma_f32_16x16x32_bf16(af[mi], bfr[nj], acc[mi][nj], 0,0,0);
  }
  #pragma unroll
  for (int mi=0;mi<4;mi++)
    #pragma unroll
    for (int nj=0;nj<NJ;nj++)
      #pragma unroll
      for (int j=0;j<4;j++){
        int row = m0 + wm + mi*16 + l4*4 + j;
        int col = n0 + wn + nj*16 + l15;
        float v = acc[mi][nj][j] + bias[col];
        if constexpr (EPI==0){ v += extra[(size_t)(row>>10)*lde + col]; outb[(size_t)row*ldo+col] = f2bf(v); }
        else if constexpr (EPI==1){ v += extra[(size_t)row*lde + col]; outf[(size_t)row*ldo+col] = v; }
        else { v = 0.5f*v*(1.f+erff(v*0.70710678118f)); outb[(size_t)row*ldo+col] = f2bf(v); }
      }
}

// ================= BIG PATH: rel-skew materialization + barrier-free 32x32 flash =================

// relskew: computes RR = Q@Er^T rows and writes the SKEWED matrix rows to global, bf16, xlog2e.
// Block r0 owns output rows: r0..r0+14 full, r0+15 for c<=r0+16, and r0-1 for c>=r0+1.
__global__ __launch_bounds__(256) void relskew(
    const ushort* __restrict__ qkv, const ushort* __restrict__ Er,
    ushort* __restrict__ srel)
{
  const int bid0 = blockIdx.x;
  const int bid = ((bid0 & 7) << 9) | (bid0 >> 3);
  const int rt = bid & 63, h = (bid>>6)&15, b = bid>>10;
  const int bh = b*16 + h;
  const int r0 = rt*16;
  const int tid = threadIdx.x, w = tid>>6, lane = tid&63;
  const int l15 = lane&15, l4 = lane>>4;
  __shared__ __align__(16) ushort T[17*1032];   // skewed rows (r0-1 .. r0+15), ldsrow = tgt-(r0-1)
  ushort* srb = srel + (size_t)bh*1024*1040;

  if (tid < 17){                                // diagonal zeros: row tgt, c = tgt+1
    int tgt = r0 - 1 + tid;
    int c = tgt + 1;
    if (tgt >= 0 && c <= 1023) T[tid*1032 + c] = 0;
  }
  const ushort* Qp = qkv + (size_t)b*1024*3200 + h*64;
  short8 qa0 = *(const short8*)(Qp + (size_t)(r0+l15)*3200 + l4*8);
  short8 qa1 = *(const short8*)(Qp + (size_t)(r0+l15)*3200 + 32 + l4*8);
  for (int t=0;t<16;++t){
    const int et = w*16 + t;
    short8 e0 = *(const short8*)(Er + (size_t)(et*16+l15)*64 + l4*8);
    short8 e1 = *(const short8*)(Er + (size_t)(et*16+l15)*64 + 32 + l4*8);
    f32x4 a0 = {0.f,0.f,0.f,0.f};
    a0 = __builtin_amdgcn_mfma_f32_16x16x32_bf16(qa0, e0, a0, 0,0,0);
    a0 = __builtin_amdgcn_mfma_f32_16x16x32_bf16(qa1, e1, a0, 0,0,0);
    const int e = et*16 + l15;
    #pragma unroll
    for (int j=0;j<4;j++){
      int lr = 4*l4 + j;
      int r = r0 + lr;
      ushort v = f2bf(a0[j] * 1.4426950408f);
      bool below = (e >= 1023 - r);             // value serves row r at c=e+r-1023, else row r-1 at c=e+r+1
      int ldsrow = below ? (lr + 1) : lr;
      int c = below ? (e + r - 1023) : (e + r + 1);
      T[ldsrow*1032 + c] = v;
    }
  }
  __syncthreads();
  const int c4 = tid*4;
  for (int i=0;i<17;++i){
    int tgt = r0 - 1 + i;
    if (tgt < 0) continue;
    int lo = (i==0) ? (r0+1) : 0;
    int hh = (i==16) ? min(r0+16,1023) : 1023;
    if (c4 >= lo && c4+3 <= hh){
      uint2 vv = *(const uint2*)&T[i*1032 + c4];
      *(uint2*)(srb + (size_t)tgt*1040 + c4) = vv;
    } else if (c4 <= hh && c4+3 >= lo){
      #pragma unroll
      for (int k2=0;k2<4;k2++){
        int c = c4 + k2;
        if (c >= lo && c <= hh) srb[(size_t)tgt*1040 + c] = T[i*1032 + c];
      }
    }
  }
}

// attn6: 4 waves x 32 q-rows, barrier-free, zero LDS, in-register softmax, vector bias loads.
__global__ __launch_bounds__(256) void attn6(
    const ushort* __restrict__ qkv, const ushort* __restrict__ srel,
    const ushort* __restrict__ Vt, ushort* __restrict__ out)
{
  const int bid0 = blockIdx.x;
  const int swz = (bid0 & 7)*64 + (bid0 >> 3);
  const int bh = swz >> 3, b = bh >> 4, h = bh & 15;
  const int rblk = (swz & 7)*128;
  const int tid = threadIdx.x, w = tid >> 6, lane = tid & 63;
  const int l31 = lane & 31, hi = lane >> 5;
  const int r = rblk + w*32 + l31;              // this lane's q-row
  const ushort* Qp = qkv + (size_t)b*1024*3200 + h*64;
  const ushort* Kp = Qp + 1024;
  const ushort* Vp = Vt + (size_t)bh*64*1152;
  const ushort* Bp = srel + (size_t)bh*1024*1040 + (size_t)r*1040 + hi*4;

  short8 qf0 = *(const short8*)(Qp + (size_t)r*3200 +      hi*8);
  short8 qf1 = *(const short8*)(Qp + (size_t)r*3200 + 16 + hi*8);
  short8 qf2 = *(const short8*)(Qp + (size_t)r*3200 + 32 + hi*8);
  short8 qf3 = *(const short8*)(Qp + (size_t)r*3200 + 48 + hi*8);

  f32x16 O0 = {}, O1 = {};
  float m = -3e38f, lsum = 0.f;

  short8 kA0 = *(const short8*)(Kp + (size_t)l31*3200 +      hi*8);
  short8 kA1 = *(const short8*)(Kp + (size_t)l31*3200 + 16 + hi*8);
  short8 kA2 = *(const short8*)(Kp + (size_t)l31*3200 + 32 + hi*8);
  short8 kA3 = *(const short8*)(Kp + (size_t)l31*3200 + 48 + hi*8);
  short8 kB0, kB1, kB2, kB3;

  auto step = [&](short8& ka0, short8& ka1, short8& ka2, short8& ka3,
                  short8& kn0, short8& kn1, short8& kn2, short8& kn3, int t){
    const int c0 = t*32;
    if (t < 31){
      const ushort* kp = Kp + (size_t)(c0 + 32 + l31)*3200 + hi*8;
      kn0 = *(const short8*)(kp);
      kn1 = *(const short8*)(kp + 16);
      kn2 = *(const short8*)(kp + 32);
      kn3 = *(const short8*)(kp + 48);
    }
    ushort4 bs[4];
    #pragma unroll
    for (int rq=0;rq<4;rq++) bs[rq] = *(const ushort4*)(Bp + c0 + rq*8);
    short8 v00 = *(const short8*)(Vp + (size_t)l31*1152      + c0 +      hi*8);
    short8 v01 = *(const short8*)(Vp + (size_t)l31*1152      + c0 + 16 + hi*8);
    short8 v10 = *(const short8*)(Vp + (size_t)(32+l31)*1152 + c0 +      hi*8);
    short8 v11 = *(const short8*)(Vp + (size_t)(32+l31)*1152 + c0 + 16 + hi*8);
    f32x16 S = {};
    S = mfma32(ka0, qf0, S);
    S = mfma32(ka1, qf1, S);
    S = mfma32(ka2, qf2, S);
    S = mfma32(ka3, qf3, S);
    float p[16];
    float tmax = -3e38f;
    #pragma unroll
    for (int rq=0;rq<4;rq++)
      #pragma unroll
      for (int j=0;j<4;j++){
        float v = fmaf(S[rq*4+j], 0.18033688f, bf2f(((const ushort*)&bs[rq])[j]));
        p[rq*4+j] = v;
        tmax = fmaxf(tmax, v);
      }
    tmax = fmaxf(tmax, __shfl_xor(tmax, 32, 64));
    if (!__all(tmax <= m + 8.f)){
      float mn = fmaxf(m, tmax);
      float scl = __builtin_amdgcn_exp2f(m - mn);
      m = mn; lsum *= scl;
      #pragma unroll
      for (int i=0;i<16;i++){ O0[i]*=scl; O1[i]*=scl; }
    }
    float tsum = 0.f;
    #pragma unroll
    for (int reg=0;reg<16;reg++){ p[reg] = __builtin_amdgcn_exp2f(p[reg]-m); tsum += p[reg]; }
    lsum += tsum;
    uint W00=cvtpk(p[0],p[1]),   W01=cvtpk(p[2],p[3]);
    uint W10=cvtpk(p[4],p[5]),   W11=cvtpk(p[6],p[7]);
    uint W20=cvtpk(p[8],p[9]),   W21=cvtpk(p[10],p[11]);
    uint W30=cvtpk(p[12],p[13]), W31=cvtpk(p[14],p[15]);
    uint x00 = (uint)__shfl_xor((int)(hi? W00 : W10), 32, 64);
    uint x01 = (uint)__shfl_xor((int)(hi? W01 : W11), 32, 64);
    uint x10 = (uint)__shfl_xor((int)(hi? W20 : W30), 32, 64);
    uint x11 = (uint)__shfl_xor((int)(hi? W21 : W31), 32, 64);
    union { uint u[4]; short8 v; } pf0, pf1;
    pf0.u[0] = hi ? x00 : W00;  pf0.u[1] = hi ? x01 : W01;
    pf0.u[2] = hi ? W10 : x00;  pf0.u[3] = hi ? W11 : x01;
    pf1.u[0] = hi ? x10 : W20;  pf1.u[1] = hi ? x11 : W21;
    pf1.u[2] = hi ? W30 : x10;  pf1.u[3] = hi ? W31 : x11;
    O0 = mfma32(v00, pf0.v, O0);
    O0 = mfma32(v01, pf1.v, O0);
    O1 = mfma32(v10, pf0.v, O1);
    O1 = mfma32(v11, pf1.v, O1);
  };
  for (int t=0;t<32;t+=2){
    step(kA0,kA1,kA2,kA3, kB0,kB1,kB2,kB3, t);
    step(kB0,kB1,kB2,kB3, kA0,kA1,kA2,kA3, t+1);
  }
  float inv = 1.f/(lsum + __shfl_xor(lsum, 32, 64));
  ushort* op = out + ((size_t)(b*1024 + r))*1152 + h*64;
  #pragma unroll
  for (int rq=0;rq<4;rq++)
    #pragma unroll
    for (int s=0;s<2;s++){
      int reg = rq*4 + s*2;
      uint w0 = cvtpk(O0[reg]*inv, O0[reg+1]*inv);
      uint w1 = cvtpk(O1[reg]*inv, O1[reg+1]*inv);
      int d = rq*8 + hi*4 + s*2;
      *(uint*)(op + d) = w0;
      *(uint*)(op + 32 + d) = w1;
    }
}

// ================= FALLBACK: R5 attention (unchanged) =================
__global__ __launch_bounds__(256,3) void attn5(
    const ushort* __restrict__ qkv, const ushort* __restrict__ Er,
    const ushort* __restrict__ Vt, ushort* __restrict__ out)
{
  const int bid0 = blockIdx.x;
  const int bid = ((bid0 & 7) << 9) | (bid0 >> 3);
  const int rt = bid & 63, h = (bid>>6)&15, b = bid>>10;
  const int bh = b*16 + h;
  const int r0 = rt*16;
  const int tid = threadIdx.x, w = tid>>6, lane = tid&63;
  const int l15 = lane&15, l4 = lane>>4;

  __shared__ ushort RRF[17568];
  __shared__ __align__(16) ushort shp[4][16][88];
  __shared__ float mlbuf[4][2][16];

  const size_t base = (size_t)b*1024*3200 + (size_t)h*64;
  const ushort* Qp = qkv + base;
  const ushort* Kp = qkv + base + 1024;
  const ushort* Vp = Vt + (size_t)bh*64*1152;

  if (tid < 16) RRF[(tid+1)*1033] = 0;

  short8 qa[2], qb[2];
  const int q1 = min(r0 + 16 + l15, 1023);
  #pragma unroll
  for (int ks=0; ks<2; ++ks){
    qa[ks] = *(const short8*)(Qp + (size_t)(r0 + l15)*3200 + ks*32 + l4*8);
    qb[ks] = *(const short8*)(Qp + (size_t)q1*3200 + ks*32 + l4*8);
  }
  short8 e0 = *(const short8*)(Er + (size_t)(w*256 + l15)*64 + l4*8);
  short8 e1 = *(const short8*)(Er + (size_t)(w*256 + l15)*64 + 32 + l4*8);
  for (int t=0; t<16; ++t){
    const int et = w*16 + t;
    short8 c0v = e0, c1v = e1;
    if (t < 15){
      e0 = *(const short8*)(Er + (size_t)((et+1)*16 + l15)*64 + l4*8);
      e1 = *(const short8*)(Er + (size_t)((et+1)*16 + l15)*64 + 32 + l4*8);
    }
    f32x4 a0 = {0.f,0.f,0.f,0.f}, a1 = {0.f,0.f,0.f,0.f};
    a0 = __builtin_amdgcn_mfma_f32_16x16x32_bf16(qa[0], c0v, a0, 0,0,0);
    a1 = __builtin_amdgcn_mfma_f32_16x16x32_bf16(qb[0], c0v, a1, 0,0,0);
    a0 = __builtin_amdgcn_mfma_f32_16x16x32_bf16(qa[1], c1v, a0, 0,0,0);
    a1 = __builtin_amdgcn_mfma_f32_16x16x32_bf16(qb[1], c1v, a1, 0,0,0);
    const int e = et*16 + l15;
    #pragma unroll
    for (int j=0;j<4;j++) RRF[(l4*4+j)*1033 + 1 + e] = f2bf(a0[j]);
    if (l4 == 0) RRF[16*1033 + 1 + e] = f2bf(a1[0]);
  }
  __syncthreads();

  float m = -1e30f, lsum = 0.f;
  f32x4 Oacc[4];
  #pragma unroll
  for (int n2=0;n2<4;n2++){ Oacc[n2][0]=0.f; Oacc[n2][1]=0.f; Oacc[n2][2]=0.f; Oacc[n2][3]=0.f; }
  const int dl = 4*l4 - l15;
  const int rbase = l15*1033;
  const int c0base = w*256;

  short8 ka[2][4][2];
  #pragma unroll
  for (int f=0;f<4;f++)
    #pragma unroll
    for (int ks=0;ks<2;ks++)
      ka[0][f][ks] = *(const short8*)(Kp + (size_t)(c0base + f*16 + l15)*3200 + ks*32 + l4*8);

  #pragma unroll
  for (int t=0;t<4;++t){
    const int cur = t&1;
    const int c0 = c0base + t*64;
    float skf[16];
    #pragma unroll
    for (int f=0;f<4;f++)
      #pragma unroll
      for (int j=0;j<4;j++){
        int d = (c0 + f*16 + j - r0) + dl;
        int off = (d<=0) ? (1024+d) : (1032+d);
        skf[f*4+j] = bf2f(RRF[rbase + off]);
      }
    f32x4 S[4];
    #pragma unroll
    for (int f=0;f<4;f++){
      S[f][0]=0.f; S[f][1]=0.f; S[f][2]=0.f; S[f][3]=0.f;
      #pragma unroll
      for (int ks=0;ks<2;ks++)
        S[f] = __builtin_amdgcn_mfma_f32_16x16x32_bf16(ka[cur][f][ks], qa[ks], S[f], 0,0,0);
    }
    if (t < 3){
      const int c2 = c0 + 64;
      #pragma unroll
      for (int f=0;f<4;f++)
        #pragma unroll
        for (int ks=0;ks<2;ks++)
          ka[cur^1][f][ks] = *(const short8*)(Kp + (size_t)(c2 + f*16 + l15)*3200 + ks*32 + l4*8);
    }
    short8 va[2][4];
    #pragma unroll
    for (int ks=0;ks<2;ks++)
      #pragma unroll
      for (int n2=0;n2<4;n2++)
        va[ks][n2] = *(const short8*)(Vp + (size_t)(n2*16 + l15)*1152 + c0 + ks*32 + l4*8);
    float tm[4];
    #pragma unroll
    for (int f=0;f<4;f++){
      float v0 = fmaf(S[f][0], 0.125f, skf[f*4+0]);
      float v1 = fmaf(S[f][1], 0.125f, skf[f*4+1]);
      float v2 = fmaf(S[f][2], 0.125f, skf[f*4+2]);
      float v3 = fmaf(S[f][3], 0.125f, skf[f*4+3]);
      S[f][0]=v0; S[f][1]=v1; S[f][2]=v2; S[f][3]=v3;
      tm[f] = fmaxf(fmaxf(v0,v1), fmaxf(v2,v3));
    }
    float tmax = fmaxf(fmaxf(tm[0],tm[1]), fmaxf(tm[2],tm[3]));
    tmax = fmaxf(tmax, __shfl_xor(tmax, 16, 64));
    tmax = fmaxf(tmax, __shfl_xor(tmax, 32, 64));
    const float mn = fmaxf(m, tmax);
    const float scl = __expf(m - mn);
    m = mn;
    float tsum = 0.f;
    #pragma unroll
    for (int f=0;f<4;f++){
      float p0 = __expf(S[f][0]-m), p1 = __expf(S[f][1]-m), p2 = __expf(S[f][2]-m), p3 = __expf(S[f][3]-m);
      tsum += (p0+p1)+(p2+p3);
      ushort4 pw = make_ushort4(f2bf(p0), f2bf(p1), f2bf(p2), f2bf(p3));
      *(ushort4*)&shp[w][l15][f*16 + l4*4] = pw;
    }
    tsum += __shfl_xor(tsum, 16, 64);
    tsum += __shfl_xor(tsum, 32, 64);
    lsum = lsum*scl + tsum;
    #pragma unroll
    for (int n2=0;n2<4;n2++)
      #pragma unroll
      for (int j=0;j<4;j++) Oacc[n2][j] *= scl;
    #pragma unroll
    for (int ks=0; ks<2; ++ks){
      short8 pb = *(const short8*)&shp[w][l15][ks*32 + l4*8];
      #pragma unroll
      for (int n2=0; n2<4; ++n2)
        Oacc[n2] = __builtin_amdgcn_mfma_f32_16x16x32_bf16(va[ks][n2], pb, Oacc[n2], 0,0,0);
    }
  }
  #pragma unroll
  for (int n2=0;n2<4;n2++){
    ushort4 ow = make_ushort4(f2bf(Oacc[n2][0]), f2bf(Oacc[n2][1]), f2bf(Oacc[n2][2]), f2bf(Oacc[n2][3]));
    *(ushort4*)&shp[w][l15][n2*16 + l4*4] = ow;
  }
  if (l4 == 0){ mlbuf[w][0][l15] = m; mlbuf[w][1][l15] = lsum; }
  __syncthreads();
  {
    const int row = tid>>4, hb = (tid&15)*4;
    float M2 = mlbuf[0][0][row];
    #pragma unroll
    for (int w2=1;w2<4;w2++) M2 = fmaxf(M2, mlbuf[w2][0][row]);
    float den = 0.f, num[4] = {0.f,0.f,0.f,0.f};
    #pragma unroll
    for (int w2=0;w2<4;w2++){
      float e = __expf(mlbuf[w2][0][row] - M2);
      den += mlbuf[w2][1][row]*e;
      ushort4 ov = *(const ushort4*)&shp[w2][row][hb];
      num[0] += bf2f(ov.x)*e; num[1] += bf2f(ov.y)*e; num[2] += bf2f(ov.z)*e; num[3] += bf2f(ov.w)*e;
    }
    float invd = 1.f/den;
    ushort4 u;
    u.x = f2bf(num[0]*invd); u.y = f2bf(num[1]*invd); u.z = f2bf(num[2]*invd); u.w = f2bf(num[3]*invd);
    *(ushort4*)&out[((size_t)(b*1024 + r0 + row))*1152 + h*64 + hb] = u;
  }
}

extern "C" void kernel_launch(void* const* d_in, const int* in_sizes, int n_in,
                              void* d_out, int out_size, void* d_ws, size_t ws_size,
                              hipStream_t stream)
{
  const float* x    = (const float*)d_in[0];
  const float* t    = (const float*)d_in[1];
  const float* ln1g = (const float*)d_in[2];
  const float* ln1b = (const float*)d_in[3];
  const float* qkvw = (const float*)d_in[4];
  const float* qkvb = (const float*)d_in[5];
  const float* timew= (const float*)d_in[6];
  const float* timeb= (const float*)d_in[7];
  const float* outw = (const float*)d_in[8];
  const float* outbv= (const float*)d_in[9];
  const float* Er   = (const float*)d_in[10];
  const float* ln2g = (const float*)d_in[11];
  const float* ln2b = (const float*)d_in[12];
  const float* ff1w = (const float*)d_in[13];
  const float* ff1b = (const float*)d_in[14];
  const float* ff2w = (const float*)d_in[15];
  const float* ff2b = (const float*)d_in[16];
  float* o = (float*)d_out;

  char* ws = (char*)d_ws;
  ushort* qkvw_t = (ushort*)(ws);              // [3072][1152]
  ushort* outw_t = (ushort*)(ws + 7077888);    // [1024][1152]
  ushort* ff1w_t = (ushort*)(ws + 9437184);    // [4096][1152]
  ushort* ff2w_t = (ushort*)(ws + 18874368);   // [1024][4224]
  ushort* er_b   = (ushort*)(ws + 27525120);   // [1024][64]
  float*  tq     = (float*) (ws + 27656192);   // [4][3072]
  ushort* bufA   = (ushort*)(ws + 27705344);   // [4096][1152]
  ushort* vt     = (ushort*)(ws + 37142528);   // [4096][1152]
  ushort* bufB   = (ushort*)(ws + 46579712);   // [4096][4224] (qkv at stride 3200 / ff1o at 4224)
  ushort* srel   = (ushort*)(ws + 81182720);   // [64][1024][1040] bf16 skewed-rel (big path only)
  const bool big = ws_size >= 217497600ull;    // 81182720 + 64*1024*1040*2

  wt_cvt<<<dim3(48,16),256,0,stream>>>(qkvw, qkvw_t, 1024, 3072, 1152);
  wt_cvt<<<dim3(16,16),256,0,stream>>>(outw, outw_t, 1024, 1024, 1152);
  wt_cvt<<<dim3(64,16),256,0,stream>>>(ff1w, ff1w_t, 1024, 4096, 1152);
  wt_cvt<<<dim3(16,64),256,0,stream>>>(ff2w, ff2w_t, 4096, 1024, 4224);
  cvt_f2b<<<256,256,0,stream>>>(Er, er_b, 65536);

  ln_rows<<<4096,256,0,stream>>>(x, ln1g, ln1b, bufA, 1152);
  tq_gemm2<<<48,256,0,stream>>>(t, timew, timeb, tq);
  gemm3<0,128><<<768,256,0,stream>>>(bufA, qkvw_t, qkvb, tq, bufB, nullptr,
                                     1024, 1152, 1152, 3200, 3072, 24);
  vt_k<<<dim3(16,64),256,0,stream>>>(bufB, vt);
  if (big){
    relskew<<<4096,256,0,stream>>>(bufB, er_b, srel);
    attn6<<<512,256,0,stream>>>(bufB, srel, vt, bufA);
  } else {
    attn5<<<4096,256,0,stream>>>(bufB, er_b, vt, bufA);
  }
  gemm3<1,64><<<512,256,0,stream>>>(bufA, outw_t, outbv, x, nullptr, o,
                                    1024, 1152, 1152, 1024, 1024, 16);
  ln_rows<<<4096,256,0,stream>>>(o, ln2g, ln2b, bufA, 1152);
  gemm3<2,128><<<1024,256,0,stream>>>(bufA, ff1w_t, ff1b, nullptr, bufB, nullptr,
                                      1024, 1152, 1152, 4224, 0, 32);
  gemm3<1,64><<<512,256,0,stream>>>(bufB, ff2w_t, ff2b, o, nullptr, o,
                                    4096, 4224, 4224, 1024, 1024, 16);
}

// Round 7
// 412.289 us; speedup vs baseline: 1.1382x; 1.0411x over previous
//
#include <hip/hip_runtime.h>
#include <hip/hip_bf16.h>

typedef __attribute__((ext_vector_type(8))) short short8;
typedef __attribute__((ext_vector_type(4))) float f32x4;
typedef __attribute__((ext_vector_type(16))) float f32x16;

#define DEV __device__ __forceinline__

DEV float bf2f(ushort u){ union { float f; unsigned int i; } x; x.i = ((unsigned int)u)<<16; return x.f; }
DEV ushort f2bf(float f){ union { float fl; unsigned int i; } x; x.fl = f; unsigned int r = x.i + 0x7fffu + ((x.i>>16)&1u); return (ushort)(r>>16); }

DEV void gl2lds16(const ushort* g, ushort* l){
  __builtin_amdgcn_global_load_lds((const __attribute__((address_space(1))) void*)g,
                                   (__attribute__((address_space(3))) void*)l, 16, 0, 0);
}
DEV f32x16 mfma32(short8 a, short8 b, f32x16 c){
  return __builtin_amdgcn_mfma_f32_32x32x16_bf16(a, b, c, 0, 0, 0);
}
DEV uint cvtpk(float lo, float hi){
  uint r; asm("v_cvt_pk_bf16_f32 %0, %1, %2" : "=v"(r) : "v"(lo), "v"(hi));
  return r;
}

// ---------------- fp32 -> bf16 convert (Er only) ----------------
__global__ void cvt_f2b(const float* __restrict__ in, ushort* __restrict__ out, int n){
  int i = blockIdx.x*blockDim.x + threadIdx.x;
  int stride = gridDim.x*blockDim.x;
  for (; i < n; i += stride) out[i] = f2bf(in[i]);
}

// ---------------- fp32 [K][N] -> bf16 [N][K+pad] tiled transpose ----------------
__global__ __launch_bounds__(256) void wt_cvt(const float* __restrict__ in, ushort* __restrict__ out,
                                              int K, int N, int ldk){
  const int n0 = blockIdx.x*64, k0 = blockIdx.y*64;
  __shared__ float T[64][65];
  const int tid = threadIdx.x;
  const int r = tid>>4, c = (tid&15)*4;
  #pragma unroll
  for (int p=0;p<4;p++){
    float4 v = *(const float4*)&in[(size_t)(k0 + p*16 + r)*N + n0 + c];
    T[p*16+r][c+0]=v.x; T[p*16+r][c+1]=v.y; T[p*16+r][c+2]=v.z; T[p*16+r][c+3]=v.w;
  }
  __syncthreads();
  #pragma unroll
  for (int p=0;p<4;p++){
    int n = p*16 + r;
    ushort u0 = f2bf(T[c+0][n]), u1 = f2bf(T[c+1][n]), u2 = f2bf(T[c+2][n]), u3 = f2bf(T[c+3][n]);
    ushort4 u = make_ushort4(u0,u1,u2,u3);
    *(ushort4*)&out[(size_t)(n0+n)*ldk + k0 + c] = u;
  }
}

// ---------------- V transpose: qkv V-part [n][hd] -> Vt [(bh*64+hd)][n] ----------------
__global__ __launch_bounds__(256) void vt_k(const ushort* __restrict__ qkv, ushort* __restrict__ vt){
  const int bh = blockIdx.y; const int b = bh>>4, h = bh&15;
  const int n0 = blockIdx.x*64;
  __shared__ ushort T[64][66];
  const int tid = threadIdx.x;
  const int r = tid>>3, c8 = (tid&7)*8;
  #pragma unroll
  for (int p=0;p<2;p++){
    int row = p*32 + r;
    short8 v = *(const short8*)&qkv[(size_t)(b*1024 + n0 + row)*3200 + 2048 + h*64 + c8];
    #pragma unroll
    for (int i=0;i<8;i++) T[row][c8+i] = ((ushort*)&v)[i];
  }
  __syncthreads();
  #pragma unroll
  for (int p=0;p<2;p++){
    int d = p*32 + r;
    union { ushort u[8]; short8 v; } o;
    #pragma unroll
    for (int i=0;i<8;i++) o.u[i] = T[c8+i][d];
    *(short8*)&vt[(size_t)(bh*64 + d)*1152 + n0 + c8] = o.v;
  }
}

// ---------------- LayerNorm over C=1024 ----------------
__global__ __launch_bounds__(256) void ln_rows(const float* __restrict__ in,
                                               const float* __restrict__ g,
                                               const float* __restrict__ bta,
                                               ushort* __restrict__ out, int ldo){
  int row = blockIdx.x; int tid = threadIdx.x;
  const float* x = in + (size_t)row*1024;
  float v[4]; float s = 0.f;
  #pragma unroll
  for (int i=0;i<4;i++){ v[i] = x[tid + 256*i]; s += v[i]; }
  __shared__ float rbuf[256];
  rbuf[tid] = s; __syncthreads();
  for (int off=128; off>0; off>>=1){ if (tid<off) rbuf[tid]+=rbuf[tid+off]; __syncthreads(); }
  float mean = rbuf[0] * (1.f/1024.f);
  __syncthreads();
  float s2 = 0.f;
  #pragma unroll
  for (int i=0;i<4;i++){ float d=v[i]-mean; s2 += d*d; }
  rbuf[tid] = s2; __syncthreads();
  for (int off=128; off>0; off>>=1){ if (tid<off) rbuf[tid]+=rbuf[tid+off]; __syncthreads(); }
  float var = rbuf[0] * (1.f/1024.f);
  float rstd = rsqrtf(var + 1e-5f);
  #pragma unroll
  for (int i=0;i<4;i++){ int c = tid+256*i; out[(size_t)row*ldo+c] = f2bf((v[i]-mean)*rstd*g[c]+bta[c]); }
}

// ---------------- time-embedding GEMM ----------------
__global__ __launch_bounds__(256) void tq_gemm2(const float* __restrict__ t, const float* __restrict__ tw,
                                                const float* __restrict__ tb, float* __restrict__ tq){
  const int tid = threadIdx.x;
  const int j = blockIdx.x*64 + (tid & 63);
  const int sl = tid >> 6;
  float acc[4] = {0.f,0.f,0.f,0.f};
  for (int k = sl*64; k < sl*64+64; ++k){
    float wv = tw[(size_t)k*3072 + j];
    #pragma unroll
    for (int b=0;b<4;b++) acc[b] = fmaf(t[b*256+k], wv, acc[b]);
  }
  __shared__ float red[4][4][64];
  #pragma unroll
  for (int b=0;b<4;b++) red[sl][b][tid&63] = acc[b];
  __syncthreads();
  if (sl == 0){
    #pragma unroll
    for (int b=0;b<4;b++)
      tq[b*3072 + j] = red[0][b][tid&63] + red[1][b][tid&63] + red[2][b][tid&63] + red[3][b][tid&63] + tb[j];
  }
}

// ---------------- gemm4: 128xTN tile, BK=32, double-buffered LDS 2-phase pipeline ----------------
// Per iteration: issue next tile's global_load_lds into buf^1, ds_read+MFMA on buf, ONE barrier.
// HBM latency of the stage hides under the MFMA cluster (catalog T3-minimum recipe).
template<int EPI, int TN>
__global__ __launch_bounds__(256) void gemm4(
    const ushort* __restrict__ A, const ushort* __restrict__ Bt,
    const float* __restrict__ bias, const float* __restrict__ extra,
    ushort* __restrict__ outb, float* __restrict__ outf,
    int K, int lda, int ldb, int ldo, int lde, int nbx)
{
  constexpr int NJ = TN/32;
  __shared__ __align__(16) ushort Al[2][128*32];
  __shared__ __align__(16) ushort Bl[2][TN*32];
  const int nwg = gridDim.x, cpx = nwg >> 3;
  const int bid = blockIdx.x;
  const int swz = (bid & 7)*cpx + (bid >> 3);
  const int m0 = (swz / nbx)*128, n0 = (swz % nbx)*TN;
  const int tid = threadIdx.x, lane = tid & 63, wid = tid >> 6;
  const int wm = (wid&1)*64, wn = (wid>>1)*(TN/2);
  const int l15 = lane&15, l4 = lane>>4;
  f32x4 acc[4][NJ];
  #pragma unroll
  for (int i=0;i<4;i++)
    #pragma unroll
    for (int jx=0;jx<NJ;jx++){ acc[i][jx][0]=0.f; acc[i][jx][1]=0.f; acc[i][jx][2]=0.f; acc[i][jx][3]=0.f; }
  const ushort* a0p = A + (size_t)(m0 + (tid>>2))*lda + (tid&3)*8;
  const ushort* a1p = A + (size_t)(m0 + 64 + (tid>>2))*lda + (tid&3)*8;
  const ushort* b0p = Bt + (size_t)(n0 + (tid>>2))*ldb + (tid&3)*8;
  const ushort* b1p = nullptr;
  if constexpr (TN==128) b1p = Bt + (size_t)(n0 + 64 + (tid>>2))*ldb + (tid&3)*8;
  const int lsl = tid*8, lsh = (tid+256)*8;

  // prologue: stage tile 0 into buffer 0
  gl2lds16(a0p, &Al[0][lsl]);
  gl2lds16(a1p, &Al[0][lsh]);
  gl2lds16(b0p, &Bl[0][lsl]);
  if constexpr (TN==128) gl2lds16(b1p, &Bl[0][lsh]);
  __syncthreads();

  const int nk = K >> 5;
  for (int it=0; it<nk; ++it){
    const int cur = it & 1;
    ushort* Ac = Al[cur];  ushort* Bc = Bl[cur];
    if (it+1 < nk){
      const int k1 = (it+1) << 5;
      gl2lds16(a0p + k1, &Al[cur^1][lsl]);
      gl2lds16(a1p + k1, &Al[cur^1][lsh]);
      gl2lds16(b0p + k1, &Bl[cur^1][lsl]);
      if constexpr (TN==128) gl2lds16(b1p + k1, &Bl[cur^1][lsh]);
    }
    short8 af[4], bfr[NJ];
    #pragma unroll
    for (int mi=0;mi<4;mi++) af[mi]  = *(const short8*)&Ac[(wm + mi*16 + l15)*32 + l4*8];
    #pragma unroll
    for (int nj=0;nj<NJ;nj++) bfr[nj] = *(const short8*)&Bc[(wn + nj*16 + l15)*32 + l4*8];
    #pragma unroll
    for (int mi=0;mi<4;mi++)
      #pragma unroll
      for (int nj=0;nj<NJ;nj++)
        acc[mi][nj] = __builtin_amdgcn_mfma_f32_16x16x32_bf16(af[mi], bfr[nj], acc[mi][nj], 0,0,0);
    __syncthreads();   // drains vmcnt(0): next tile's stage (issued above) lands; buf reuse safe
  }
  #pragma unroll
  for (int mi=0;mi<4;mi++)
    #pragma unroll
    for (int nj=0;nj<NJ;nj++)
      #pragma unroll
      for (int j=0;j<4;j++){
        int row = m0 + wm + mi*16 + l4*4 + j;
        int col = n0 + wn + nj*16 + l15;
        float v = acc[mi][nj][j] + bias[col];
        if constexpr (EPI==0){ v += extra[(size_t)(row>>10)*lde + col]; outb[(size_t)row*ldo+col] = f2bf(v); }
        else if constexpr (EPI==1){ v += extra[(size_t)row*lde + col]; outf[(size_t)row*ldo+col] = v; }
        else { v = 0.5f*v*(1.f+erff(v*0.70710678118f)); outb[(size_t)row*ldo+col] = f2bf(v); }
      }
}

// ================= BIG PATH: rel-skew materialization + barrier-free 32x32 flash =================

__global__ __launch_bounds__(256) void relskew(
    const ushort* __restrict__ qkv, const ushort* __restrict__ Er,
    ushort* __restrict__ srel)
{
  const int bid0 = blockIdx.x;
  const int bid = ((bid0 & 7) << 9) | (bid0 >> 3);
  const int rt = bid & 63, h = (bid>>6)&15, b = bid>>10;
  const int bh = b*16 + h;
  const int r0 = rt*16;
  const int tid = threadIdx.x, w = tid>>6, lane = tid&63;
  const int l15 = lane&15, l4 = lane>>4;
  __shared__ __align__(16) ushort T[17*1032];   // skewed rows (r0-1 .. r0+15)
  ushort* srb = srel + (size_t)bh*1024*1040;

  if (tid < 17){
    int tgt = r0 - 1 + tid;
    int c = tgt + 1;
    if (tgt >= 0 && c <= 1023) T[tid*1032 + c] = 0;
  }
  const ushort* Qp = qkv + (size_t)b*1024*3200 + h*64;
  short8 qa0 = *(const short8*)(Qp + (size_t)(r0+l15)*3200 + l4*8);
  short8 qa1 = *(const short8*)(Qp + (size_t)(r0+l15)*3200 + 32 + l4*8);
  for (int t=0;t<16;++t){
    const int et = w*16 + t;
    short8 e0 = *(const short8*)(Er + (size_t)(et*16+l15)*64 + l4*8);
    short8 e1 = *(const short8*)(Er + (size_t)(et*16+l15)*64 + 32 + l4*8);
    f32x4 a0 = {0.f,0.f,0.f,0.f};
    a0 = __builtin_amdgcn_mfma_f32_16x16x32_bf16(qa0, e0, a0, 0,0,0);
    a0 = __builtin_amdgcn_mfma_f32_16x16x32_bf16(qa1, e1, a0, 0,0,0);
    const int e = et*16 + l15;
    #pragma unroll
    for (int j=0;j<4;j++){
      int lr = 4*l4 + j;
      int r = r0 + lr;
      ushort v = f2bf(a0[j] * 1.4426950408f);
      bool below = (e >= 1023 - r);
      int ldsrow = below ? (lr + 1) : lr;
      int c = below ? (e + r - 1023) : (e + r + 1);
      T[ldsrow*1032 + c] = v;
    }
  }
  __syncthreads();
  const int c4 = tid*4;
  for (int i=0;i<17;++i){
    int tgt = r0 - 1 + i;
    if (tgt < 0) continue;
    int lo = (i==0) ? (r0+1) : 0;
    int hh = (i==16) ? min(r0+16,1023) : 1023;
    if (c4 >= lo && c4+3 <= hh){
      uint2 vv = *(const uint2*)&T[i*1032 + c4];
      *(uint2*)(srb + (size_t)tgt*1040 + c4) = vv;
    } else if (c4 <= hh && c4+3 >= lo){
      #pragma unroll
      for (int k2=0;k2<4;k2++){
        int c = c4 + k2;
        if (c >= lo && c <= hh) srb[(size_t)tgt*1040 + c] = T[i*1032 + c];
      }
    }
  }
}

// attn6: 4 waves x 32 q-rows, barrier-free, zero LDS, in-register softmax, vector bias loads.
__global__ __launch_bounds__(256) void attn6(
    const ushort* __restrict__ qkv, const ushort* __restrict__ srel,
    const ushort* __restrict__ Vt, ushort* __restrict__ out)
{
  const int bid0 = blockIdx.x;
  const int swz = (bid0 & 7)*64 + (bid0 >> 3);
  const int bh = swz >> 3, b = bh >> 4, h = bh & 15;
  const int rblk = (swz & 7)*128;
  const int tid = threadIdx.x, w = tid >> 6, lane = tid & 63;
  const int l31 = lane & 31, hi = lane >> 5;
  const int r = rblk + w*32 + l31;
  const ushort* Qp = qkv + (size_t)b*1024*3200 + h*64;
  const ushort* Kp = Qp + 1024;
  const ushort* Vp = Vt + (size_t)bh*64*1152;
  const ushort* Bp = srel + (size_t)bh*1024*1040 + (size_t)r*1040 + hi*4;

  short8 qf0 = *(const short8*)(Qp + (size_t)r*3200 +      hi*8);
  short8 qf1 = *(const short8*)(Qp + (size_t)r*3200 + 16 + hi*8);
  short8 qf2 = *(const short8*)(Qp + (size_t)r*3200 + 32 + hi*8);
  short8 qf3 = *(const short8*)(Qp + (size_t)r*3200 + 48 + hi*8);

  f32x16 O0 = {}, O1 = {};
  float m = -3e38f, lsum = 0.f;

  short8 kA0 = *(const short8*)(Kp + (size_t)l31*3200 +      hi*8);
  short8 kA1 = *(const short8*)(Kp + (size_t)l31*3200 + 16 + hi*8);
  short8 kA2 = *(const short8*)(Kp + (size_t)l31*3200 + 32 + hi*8);
  short8 kA3 = *(const short8*)(Kp + (size_t)l31*3200 + 48 + hi*8);
  short8 kB0, kB1, kB2, kB3;

  auto step = [&](short8& ka0, short8& ka1, short8& ka2, short8& ka3,
                  short8& kn0, short8& kn1, short8& kn2, short8& kn3, int t){
    const int c0 = t*32;
    if (t < 31){
      const ushort* kp = Kp + (size_t)(c0 + 32 + l31)*3200 + hi*8;
      kn0 = *(const short8*)(kp);
      kn1 = *(const short8*)(kp + 16);
      kn2 = *(const short8*)(kp + 32);
      kn3 = *(const short8*)(kp + 48);
    }
    ushort4 bs[4];
    #pragma unroll
    for (int rq=0;rq<4;rq++) bs[rq] = *(const ushort4*)(Bp + c0 + rq*8);
    short8 v00 = *(const short8*)(Vp + (size_t)l31*1152      + c0 +      hi*8);
    short8 v01 = *(const short8*)(Vp + (size_t)l31*1152      + c0 + 16 + hi*8);
    short8 v10 = *(const short8*)(Vp + (size_t)(32+l31)*1152 + c0 +      hi*8);
    short8 v11 = *(const short8*)(Vp + (size_t)(32+l31)*1152 + c0 + 16 + hi*8);
    f32x16 S = {};
    S = mfma32(ka0, qf0, S);
    S = mfma32(ka1, qf1, S);
    S = mfma32(ka2, qf2, S);
    S = mfma32(ka3, qf3, S);
    float p[16];
    float tmax = -3e38f;
    #pragma unroll
    for (int rq=0;rq<4;rq++)
      #pragma unroll
      for (int j=0;j<4;j++){
        float v = fmaf(S[rq*4+j], 0.18033688f, bf2f(((const ushort*)&bs[rq])[j]));
        p[rq*4+j] = v;
        tmax = fmaxf(tmax, v);
      }
    tmax = fmaxf(tmax, __shfl_xor(tmax, 32, 64));
    if (!__all(tmax <= m + 8.f)){
      float mn = fmaxf(m, tmax);
      float scl = __builtin_amdgcn_exp2f(m - mn);
      m = mn; lsum *= scl;
      #pragma unroll
      for (int i=0;i<16;i++){ O0[i]*=scl; O1[i]*=scl; }
    }
    float tsum = 0.f;
    #pragma unroll
    for (int reg=0;reg<16;reg++){ p[reg] = __builtin_amdgcn_exp2f(p[reg]-m); tsum += p[reg]; }
    lsum += tsum;
    uint W00=cvtpk(p[0],p[1]),   W01=cvtpk(p[2],p[3]);
    uint W10=cvtpk(p[4],p[5]),   W11=cvtpk(p[6],p[7]);
    uint W20=cvtpk(p[8],p[9]),   W21=cvtpk(p[10],p[11]);
    uint W30=cvtpk(p[12],p[13]), W31=cvtpk(p[14],p[15]);
    uint x00 = (uint)__shfl_xor((int)(hi? W00 : W10), 32, 64);
    uint x01 = (uint)__shfl_xor((int)(hi? W01 : W11), 32, 64);
    uint x10 = (uint)__shfl_xor((int)(hi? W20 : W30), 32, 64);
    uint x11 = (uint)__shfl_xor((int)(hi? W21 : W31), 32, 64);
    union { uint u[4]; short8 v; } pf0, pf1;
    pf0.u[0] = hi ? x00 : W00;  pf0.u[1] = hi ? x01 : W01;
    pf0.u[2] = hi ? W10 : x00;  pf0.u[3] = hi ? W11 : x01;
    pf1.u[0] = hi ? x10 : W20;  pf1.u[1] = hi ? x11 : W21;
    pf1.u[2] = hi ? W30 : x10;  pf1.u[3] = hi ? W31 : x11;
    O0 = mfma32(v00, pf0.v, O0);
    O0 = mfma32(v01, pf1.v, O0);
    O1 = mfma32(v10, pf0.v, O1);
    O1 = mfma32(v11, pf1.v, O1);
  };
  for (int t=0;t<32;t+=2){
    step(kA0,kA1,kA2,kA3, kB0,kB1,kB2,kB3, t);
    step(kB0,kB1,kB2,kB3, kA0,kA1,kA2,kA3, t+1);
  }
  float inv = 1.f/(lsum + __shfl_xor(lsum, 32, 64));
  ushort* op = out + ((size_t)(b*1024 + r))*1152 + h*64;
  #pragma unroll
  for (int rq=0;rq<4;rq++)
    #pragma unroll
    for (int s=0;s<2;s++){
      int reg = rq*4 + s*2;
      uint w0 = cvtpk(O0[reg]*inv, O0[reg+1]*inv);
      uint w1 = cvtpk(O1[reg]*inv, O1[reg+1]*inv);
      int d = rq*8 + hi*4 + s*2;
      *(uint*)(op + d) = w0;
      *(uint*)(op + 32 + d) = w1;
    }
}

// ================= FALLBACK: R5 attention (unchanged) =================
__global__ __launch_bounds__(256,3) void attn5(
    const ushort* __restrict__ qkv, const ushort* __restrict__ Er,
    const ushort* __restrict__ Vt, ushort* __restrict__ out)
{
  const int bid0 = blockIdx.x;
  const int bid = ((bid0 & 7) << 9) | (bid0 >> 3);
  const int rt = bid & 63, h = (bid>>6)&15, b = bid>>10;
  const int bh = b*16 + h;
  const int r0 = rt*16;
  const int tid = threadIdx.x, w = tid>>6, lane = tid&63;
  const int l15 = lane&15, l4 = lane>>4;

  __shared__ ushort RRF[17568];
  __shared__ __align__(16) ushort shp[4][16][88];
  __shared__ float mlbuf[4][2][16];

  const size_t base = (size_t)b*1024*3200 + (size_t)h*64;
  const ushort* Qp = qkv + base;
  const ushort* Kp = qkv + base + 1024;
  const ushort* Vp = Vt + (size_t)bh*64*1152;

  if (tid < 16) RRF[(tid+1)*1033] = 0;

  short8 qa[2], qb[2];
  const int q1 = min(r0 + 16 + l15, 1023);
  #pragma unroll
  for (int ks=0; ks<2; ++ks){
    qa[ks] = *(const short8*)(Qp + (size_t)(r0 + l15)*3200 + ks*32 + l4*8);
    qb[ks] = *(const short8*)(Qp + (size_t)q1*3200 + ks*32 + l4*8);
  }
  short8 e0 = *(const short8*)(Er + (size_t)(w*256 + l15)*64 + l4*8);
  short8 e1 = *(const short8*)(Er + (size_t)(w*256 + l15)*64 + 32 + l4*8);
  for (int t=0; t<16; ++t){
    const int et = w*16 + t;
    short8 c0v = e0, c1v = e1;
    if (t < 15){
      e0 = *(const short8*)(Er + (size_t)((et+1)*16 + l15)*64 + l4*8);
      e1 = *(const short8*)(Er + (size_t)((et+1)*16 + l15)*64 + 32 + l4*8);
    }
    f32x4 a0 = {0.f,0.f,0.f,0.f}, a1 = {0.f,0.f,0.f,0.f};
    a0 = __builtin_amdgcn_mfma_f32_16x16x32_bf16(qa[0], c0v, a0, 0,0,0);
    a1 = __builtin_amdgcn_mfma_f32_16x16x32_bf16(qb[0], c0v, a1, 0,0,0);
    a0 = __builtin_amdgcn_mfma_f32_16x16x32_bf16(qa[1], c1v, a0, 0,0,0);
    a1 = __builtin_amdgcn_mfma_f32_16x16x32_bf16(qb[1], c1v, a1, 0,0,0);
    const int e = et*16 + l15;
    #pragma unroll
    for (int j=0;j<4;j++) RRF[(l4*4+j)*1033 + 1 + e] = f2bf(a0[j]);
    if (l4 == 0) RRF[16*1033 + 1 + e] = f2bf(a1[0]);
  }
  __syncthreads();

  float m = -1e30f, lsum = 0.f;
  f32x4 Oacc[4];
  #pragma unroll
  for (int n2=0;n2<4;n2++){ Oacc[n2][0]=0.f; Oacc[n2][1]=0.f; Oacc[n2][2]=0.f; Oacc[n2][3]=0.f; }
  const int dl = 4*l4 - l15;
  const int rbase = l15*1033;
  const int c0base = w*256;

  short8 ka[2][4][2];
  #pragma unroll
  for (int f=0;f<4;f++)
    #pragma unroll
    for (int ks=0;ks<2;ks++)
      ka[0][f][ks] = *(const short8*)(Kp + (size_t)(c0base + f*16 + l15)*3200 + ks*32 + l4*8);

  #pragma unroll
  for (int t=0;t<4;++t){
    const int cur = t&1;
    const int c0 = c0base + t*64;
    float skf[16];
    #pragma unroll
    for (int f=0;f<4;f++)
      #pragma unroll
      for (int j=0;j<4;j++){
        int d = (c0 + f*16 + j - r0) + dl;
        int off = (d<=0) ? (1024+d) : (1032+d);
        skf[f*4+j] = bf2f(RRF[rbase + off]);
      }
    f32x4 S[4];
    #pragma unroll
    for (int f=0;f<4;f++){
      S[f][0]=0.f; S[f][1]=0.f; S[f][2]=0.f; S[f][3]=0.f;
      #pragma unroll
      for (int ks=0;ks<2;ks++)
        S[f] = __builtin_amdgcn_mfma_f32_16x16x32_bf16(ka[cur][f][ks], qa[ks], S[f], 0,0,0);
    }
    if (t < 3){
      const int c2 = c0 + 64;
      #pragma unroll
      for (int f=0;f<4;f++)
        #pragma unroll
        for (int ks=0;ks<2;ks++)
          ka[cur^1][f][ks] = *(const short8*)(Kp + (size_t)(c2 + f*16 + l15)*3200 + ks*32 + l4*8);
    }
    short8 va[2][4];
    #pragma unroll
    for (int ks=0;ks<2;ks++)
      #pragma unroll
      for (int n2=0;n2<4;n2++)
        va[ks][n2] = *(const short8*)(Vp + (size_t)(n2*16 + l15)*1152 + c0 + ks*32 + l4*8);
    float tm[4];
    #pragma unroll
    for (int f=0;f<4;f++){
      float v0 = fmaf(S[f][0], 0.125f, skf[f*4+0]);
      float v1 = fmaf(S[f][1], 0.125f, skf[f*4+1]);
      float v2 = fmaf(S[f][2], 0.125f, skf[f*4+2]);
      float v3 = fmaf(S[f][3], 0.125f, skf[f*4+3]);
      S[f][0]=v0; S[f][1]=v1; S[f][2]=v2; S[f][3]=v3;
      tm[f] = fmaxf(fmaxf(v0,v1), fmaxf(v2,v3));
    }
    float tmax = fmaxf(fmaxf(tm[0],tm[1]), fmaxf(tm[2],tm[3]));
    tmax = fmaxf(tmax, __shfl_xor(tmax, 16, 64));
    tmax = fmaxf(tmax, __shfl_xor(tmax, 32, 64));
    const float mn = fmaxf(m, tmax);
    const float scl = __expf(m - mn);
    m = mn;
    float tsum = 0.f;
    #pragma unroll
    for (int f=0;f<4;f++){
      float p0 = __expf(S[f][0]-m), p1 = __expf(S[f][1]-m), p2 = __expf(S[f][2]-m), p3 = __expf(S[f][3]-m);
      tsum += (p0+p1)+(p2+p3);
      ushort4 pw = make_ushort4(f2bf(p0), f2bf(p1), f2bf(p2), f2bf(p3));
      *(ushort4*)&shp[w][l15][f*16 + l4*4] = pw;
    }
    tsum += __shfl_xor(tsum, 16, 64);
    tsum += __shfl_xor(tsum, 32, 64);
    lsum = lsum*scl + tsum;
    #pragma unroll
    for (int n2=0;n2<4;n2++)
      #pragma unroll
      for (int j=0;j<4;j++) Oacc[n2][j] *= scl;
    #pragma unroll
    for (int ks=0; ks<2; ++ks){
      short8 pb = *(const short8*)&shp[w][l15][ks*32 + l4*8];
      #pragma unroll
      for (int n2=0; n2<4; ++n2)
        Oacc[n2] = __builtin_amdgcn_mfma_f32_16x16x32_bf16(va[ks][n2], pb, Oacc[n2], 0,0,0);
    }
  }
  #pragma unroll
  for (int n2=0;n2<4;n2++){
    ushort4 ow = make_ushort4(f2bf(Oacc[n2][0]), f2bf(Oacc[n2][1]), f2bf(Oacc[n2][2]), f2bf(Oacc[n2][3]));
    *(ushort4*)&shp[w][l15][n2*16 + l4*4] = ow;
  }
  if (l4 == 0){ mlbuf[w][0][l15] = m; mlbuf[w][1][l15] = lsum; }
  __syncthreads();
  {
    const int row = tid>>4, hb = (tid&15)*4;
    float M2 = mlbuf[0][0][row];
    #pragma unroll
    for (int w2=1;w2<4;w2++) M2 = fmaxf(M2, mlbuf[w2][0][row]);
    float den = 0.f, num[4] = {0.f,0.f,0.f,0.f};
    #pragma unroll
    for (int w2=0;w2<4;w2++){
      float e = __expf(mlbuf[w2][0][row] - M2);
      den += mlbuf[w2][1][row]*e;
      ushort4 ov = *(const ushort4*)&shp[w2][row][hb];
      num[0] += bf2f(ov.x)*e; num[1] += bf2f(ov.y)*e; num[2] += bf2f(ov.z)*e; num[3] += bf2f(ov.w)*e;
    }
    float invd = 1.f/den;
    ushort4 u;
    u.x = f2bf(num[0]*invd); u.y = f2bf(num[1]*invd); u.z = f2bf(num[2]*invd); u.w = f2bf(num[3]*invd);
    *(ushort4*)&out[((size_t)(b*1024 + r0 + row))*1152 + h*64 + hb] = u;
  }
}

extern "C" void kernel_launch(void* const* d_in, const int* in_sizes, int n_in,
                              void* d_out, int out_size, void* d_ws, size_t ws_size,
                              hipStream_t stream)
{
  const float* x    = (const float*)d_in[0];
  const float* t    = (const float*)d_in[1];
  const float* ln1g = (const float*)d_in[2];
  const float* ln1b = (const float*)d_in[3];
  const float* qkvw = (const float*)d_in[4];
  const float* qkvb = (const float*)d_in[5];
  const float* timew= (const float*)d_in[6];
  const float* timeb= (const float*)d_in[7];
  const float* outw = (const float*)d_in[8];
  const float* outbv= (const float*)d_in[9];
  const float* Er   = (const float*)d_in[10];
  const float* ln2g = (const float*)d_in[11];
  const float* ln2b = (const float*)d_in[12];
  const float* ff1w = (const float*)d_in[13];
  const float* ff1b = (const float*)d_in[14];
  const float* ff2w = (const float*)d_in[15];
  const float* ff2b = (const float*)d_in[16];
  float* o = (float*)d_out;

  char* ws = (char*)d_ws;
  ushort* qkvw_t = (ushort*)(ws);              // [3072][1152]
  ushort* outw_t = (ushort*)(ws + 7077888);    // [1024][1152]
  ushort* ff1w_t = (ushort*)(ws + 9437184);    // [4096][1152]
  ushort* ff2w_t = (ushort*)(ws + 18874368);   // [1024][4224]
  ushort* er_b   = (ushort*)(ws + 27525120);   // [1024][64]
  float*  tq     = (float*) (ws + 27656192);   // [4][3072]
  ushort* bufA   = (ushort*)(ws + 27705344);   // [4096][1152]
  ushort* vt     = (ushort*)(ws + 37142528);   // [4096][1152]
  ushort* bufB   = (ushort*)(ws + 46579712);   // [4096][4224] (qkv at stride 3200 / ff1o at 4224)
  ushort* srel   = (ushort*)(ws + 81182720);   // [64][1024][1040] bf16 skewed-rel (big path only)
  const bool big = ws_size >= 217497600ull;

  wt_cvt<<<dim3(48,16),256,0,stream>>>(qkvw, qkvw_t, 1024, 3072, 1152);
  wt_cvt<<<dim3(16,16),256,0,stream>>>(outw, outw_t, 1024, 1024, 1152);
  wt_cvt<<<dim3(64,16),256,0,stream>>>(ff1w, ff1w_t, 1024, 4096, 1152);
  wt_cvt<<<dim3(16,64),256,0,stream>>>(ff2w, ff2w_t, 4096, 1024, 4224);
  cvt_f2b<<<256,256,0,stream>>>(Er, er_b, 65536);

  ln_rows<<<4096,256,0,stream>>>(x, ln1g, ln1b, bufA, 1152);
  tq_gemm2<<<48,256,0,stream>>>(t, timew, timeb, tq);
  gemm4<0,128><<<768,256,0,stream>>>(bufA, qkvw_t, qkvb, tq, bufB, nullptr,
                                     1024, 1152, 1152, 3200, 3072, 24);
  vt_k<<<dim3(16,64),256,0,stream>>>(bufB, vt);
  if (big){
    relskew<<<4096,256,0,stream>>>(bufB, er_b, srel);
    attn6<<<512,256,0,stream>>>(bufB, srel, vt, bufA);
  } else {
    attn5<<<4096,256,0,stream>>>(bufB, er_b, vt, bufA);
  }
  gemm4<1,64><<<512,256,0,stream>>>(bufA, outw_t, outbv, x, nullptr, o,
                                    1024, 1152, 1152, 1024, 1024, 16);
  ln_rows<<<4096,256,0,stream>>>(o, ln2g, ln2b, bufA, 1152);
  gemm4<2,128><<<1024,256,0,stream>>>(bufA, ff1w_t, ff1b, nullptr, bufB, nullptr,
                                      1024, 1152, 1152, 4224, 0, 32);
  gemm4<1,64><<<512,256,0,stream>>>(bufB, ff2w_t, ff2b, o, nullptr, o,
                                    4096, 4224, 4224, 1024, 1024, 16);
}

// Round 8
// 395.121 us; speedup vs baseline: 1.1876x; 1.0434x over previous
//
#include <hip/hip_runtime.h>
#include <hip/hip_bf16.h>

typedef __attribute__((ext_vector_type(8))) short short8;
typedef __attribute__((ext_vector_type(4))) float f32x4;
typedef __attribute__((ext_vector_type(16))) float f32x16;

#define DEV __device__ __forceinline__

DEV float bf2f(ushort u){ union { float f; unsigned int i; } x; x.i = ((unsigned int)u)<<16; return x.f; }
DEV ushort f2bf(float f){ union { float fl; unsigned int i; } x; x.fl = f; unsigned int r = x.i + 0x7fffu + ((x.i>>16)&1u); return (ushort)(r>>16); }

DEV void gl2lds16(const ushort* g, ushort* l){
  __builtin_amdgcn_global_load_lds((const __attribute__((address_space(1))) void*)g,
                                   (__attribute__((address_space(3))) void*)l, 16, 0, 0);
}
DEV f32x16 mfma32(short8 a, short8 b, f32x16 c){
  return __builtin_amdgcn_mfma_f32_32x32x16_bf16(a, b, c, 0, 0, 0);
}
DEV uint cvtpk(float lo, float hi){
  uint r; asm("v_cvt_pk_bf16_f32 %0, %1, %2" : "=v"(r) : "v"(lo), "v"(hi));
  return r;
}

// ---------------- fp32 -> bf16 convert (Er only) ----------------
__global__ void cvt_f2b(const float* __restrict__ in, ushort* __restrict__ out, int n){
  int i = blockIdx.x*blockDim.x + threadIdx.x;
  int stride = gridDim.x*blockDim.x;
  for (; i < n; i += stride) out[i] = f2bf(in[i]);
}

// ---------------- fp32 [K][N] -> bf16 [N][K+pad] tiled transpose ----------------
__global__ __launch_bounds__(256) void wt_cvt(const float* __restrict__ in, ushort* __restrict__ out,
                                              int K, int N, int ldk){
  const int n0 = blockIdx.x*64, k0 = blockIdx.y*64;
  __shared__ float T[64][65];
  const int tid = threadIdx.x;
  const int r = tid>>4, c = (tid&15)*4;
  #pragma unroll
  for (int p=0;p<4;p++){
    float4 v = *(const float4*)&in[(size_t)(k0 + p*16 + r)*N + n0 + c];
    T[p*16+r][c+0]=v.x; T[p*16+r][c+1]=v.y; T[p*16+r][c+2]=v.z; T[p*16+r][c+3]=v.w;
  }
  __syncthreads();
  #pragma unroll
  for (int p=0;p<4;p++){
    int n = p*16 + r;
    ushort u0 = f2bf(T[c+0][n]), u1 = f2bf(T[c+1][n]), u2 = f2bf(T[c+2][n]), u3 = f2bf(T[c+3][n]);
    ushort4 u = make_ushort4(u0,u1,u2,u3);
    *(ushort4*)&out[(size_t)(n0+n)*ldk + k0 + c] = u;
  }
}

// ---------------- V transpose: qkv V-part [n][hd] -> Vt [(bh*64+hd)][n] ----------------
__global__ __launch_bounds__(256) void vt_k(const ushort* __restrict__ qkv, ushort* __restrict__ vt){
  const int bh = blockIdx.y; const int b = bh>>4, h = bh&15;
  const int n0 = blockIdx.x*64;
  __shared__ ushort T[64][66];
  const int tid = threadIdx.x;
  const int r = tid>>3, c8 = (tid&7)*8;
  #pragma unroll
  for (int p=0;p<2;p++){
    int row = p*32 + r;
    short8 v = *(const short8*)&qkv[(size_t)(b*1024 + n0 + row)*3200 + 2048 + h*64 + c8];
    #pragma unroll
    for (int i=0;i<8;i++) T[row][c8+i] = ((ushort*)&v)[i];
  }
  __syncthreads();
  #pragma unroll
  for (int p=0;p<2;p++){
    int d = p*32 + r;
    union { ushort u[8]; short8 v; } o;
    #pragma unroll
    for (int i=0;i<8;i++) o.u[i] = T[c8+i][d];
    *(short8*)&vt[(size_t)(bh*64 + d)*1152 + n0 + c8] = o.v;
  }
}

// ---------------- LayerNorm over C=1024 ----------------
__global__ __launch_bounds__(256) void ln_rows(const float* __restrict__ in,
                                               const float* __restrict__ g,
                                               const float* __restrict__ bta,
                                               ushort* __restrict__ out, int ldo){
  int row = blockIdx.x; int tid = threadIdx.x;
  const float* x = in + (size_t)row*1024;
  float v[4]; float s = 0.f;
  #pragma unroll
  for (int i=0;i<4;i++){ v[i] = x[tid + 256*i]; s += v[i]; }
  __shared__ float rbuf[256];
  rbuf[tid] = s; __syncthreads();
  for (int off=128; off>0; off>>=1){ if (tid<off) rbuf[tid]+=rbuf[tid+off]; __syncthreads(); }
  float mean = rbuf[0] * (1.f/1024.f);
  __syncthreads();
  float s2 = 0.f;
  #pragma unroll
  for (int i=0;i<4;i++){ float d=v[i]-mean; s2 += d*d; }
  rbuf[tid] = s2; __syncthreads();
  for (int off=128; off>0; off>>=1){ if (tid<off) rbuf[tid]+=rbuf[tid+off]; __syncthreads(); }
  float var = rbuf[0] * (1.f/1024.f);
  float rstd = rsqrtf(var + 1e-5f);
  #pragma unroll
  for (int i=0;i<4;i++){ int c = tid+256*i; out[(size_t)row*ldo+c] = f2bf((v[i]-mean)*rstd*g[c]+bta[c]); }
}

// ---------------- time-embedding GEMM ----------------
__global__ __launch_bounds__(256) void tq_gemm2(const float* __restrict__ t, const float* __restrict__ tw,
                                                const float* __restrict__ tb, float* __restrict__ tq){
  const int tid = threadIdx.x;
  const int j = blockIdx.x*64 + (tid & 63);
  const int sl = tid >> 6;
  float acc[4] = {0.f,0.f,0.f,0.f};
  for (int k = sl*64; k < sl*64+64; ++k){
    float wv = tw[(size_t)k*3072 + j];
    #pragma unroll
    for (int b=0;b<4;b++) acc[b] = fmaf(t[b*256+k], wv, acc[b]);
  }
  __shared__ float red[4][4][64];
  #pragma unroll
  for (int b=0;b<4;b++) red[sl][b][tid&63] = acc[b];
  __syncthreads();
  if (sl == 0){
    #pragma unroll
    for (int b=0;b<4;b++)
      tq[b*3072 + j] = red[0][b][tid&63] + red[1][b][tid&63] + red[2][b][tid&63] + red[3][b][tid&63] + tb[j];
  }
}

// ---------------- gemm4: 128xTN tile, BK=32, double-buffered LDS 2-phase pipeline ----------------
template<int EPI, int TN>
__global__ __launch_bounds__(256) void gemm4(
    const ushort* __restrict__ A, const ushort* __restrict__ Bt,
    const float* __restrict__ bias, const float* __restrict__ extra,
    ushort* __restrict__ outb, float* __restrict__ outf,
    int K, int lda, int ldb, int ldo, int lde, int nbx)
{
  constexpr int NJ = TN/32;
  __shared__ __align__(16) ushort Al[2][128*32];
  __shared__ __align__(16) ushort Bl[2][TN*32];
  const int nwg = gridDim.x, cpx = nwg >> 3;
  const int bid = blockIdx.x;
  const int swz = (bid & 7)*cpx + (bid >> 3);
  const int m0 = (swz / nbx)*128, n0 = (swz % nbx)*TN;
  const int tid = threadIdx.x, lane = tid & 63, wid = tid >> 6;
  const int wm = (wid&1)*64, wn = (wid>>1)*(TN/2);
  const int l15 = lane&15, l4 = lane>>4;
  f32x4 acc[4][NJ];
  #pragma unroll
  for (int i=0;i<4;i++)
    #pragma unroll
    for (int jx=0;jx<NJ;jx++){ acc[i][jx][0]=0.f; acc[i][jx][1]=0.f; acc[i][jx][2]=0.f; acc[i][jx][3]=0.f; }
  const ushort* a0p = A + (size_t)(m0 + (tid>>2))*lda + (tid&3)*8;
  const ushort* a1p = A + (size_t)(m0 + 64 + (tid>>2))*lda + (tid&3)*8;
  const ushort* b0p = Bt + (size_t)(n0 + (tid>>2))*ldb + (tid&3)*8;
  const ushort* b1p = nullptr;
  if constexpr (TN==128) b1p = Bt + (size_t)(n0 + 64 + (tid>>2))*ldb + (tid&3)*8;
  const int lsl = tid*8, lsh = (tid+256)*8;

  gl2lds16(a0p, &Al[0][lsl]);
  gl2lds16(a1p, &Al[0][lsh]);
  gl2lds16(b0p, &Bl[0][lsl]);
  if constexpr (TN==128) gl2lds16(b1p, &Bl[0][lsh]);
  __syncthreads();

  const int nk = K >> 5;
  for (int it=0; it<nk; ++it){
    const int cur = it & 1;
    ushort* Ac = Al[cur];  ushort* Bc = Bl[cur];
    if (it+1 < nk){
      const int k1 = (it+1) << 5;
      gl2lds16(a0p + k1, &Al[cur^1][lsl]);
      gl2lds16(a1p + k1, &Al[cur^1][lsh]);
      gl2lds16(b0p + k1, &Bl[cur^1][lsl]);
      if constexpr (TN==128) gl2lds16(b1p + k1, &Bl[cur^1][lsh]);
    }
    short8 af[4], bfr[NJ];
    #pragma unroll
    for (int mi=0;mi<4;mi++) af[mi]  = *(const short8*)&Ac[(wm + mi*16 + l15)*32 + l4*8];
    #pragma unroll
    for (int nj=0;nj<NJ;nj++) bfr[nj] = *(const short8*)&Bc[(wn + nj*16 + l15)*32 + l4*8];
    #pragma unroll
    for (int mi=0;mi<4;mi++)
      #pragma unroll
      for (int nj=0;nj<NJ;nj++)
        acc[mi][nj] = __builtin_amdgcn_mfma_f32_16x16x32_bf16(af[mi], bfr[nj], acc[mi][nj], 0,0,0);
    __syncthreads();
  }
  #pragma unroll
  for (int mi=0;mi<4;mi++)
    #pragma unroll
    for (int nj=0;nj<NJ;nj++)
      #pragma unroll
      for (int j=0;j<4;j++){
        int row = m0 + wm + mi*16 + l4*4 + j;
        int col = n0 + wn + nj*16 + l15;
        float v = acc[mi][nj][j] + bias[col];
        if constexpr (EPI==0){ v += extra[(size_t)(row>>10)*lde + col]; outb[(size_t)row*ldo+col] = f2bf(v); }
        else if constexpr (EPI==1){ v += extra[(size_t)row*lde + col]; outf[(size_t)row*ldo+col] = v; }
        else { v = 0.5f*v*(1.f+erff(v*0.70710678118f)); outb[(size_t)row*ldo+col] = f2bf(v); }
      }
}

// ---------------- attn7: fused rel-skew (LDS) + 32x32 in-register-softmax flash ----------------
// grid 2048 = 64 bh x 32 row-tiles of 32 q-rows; 4 waves split kv 4-way, merge at end.
// RRF layout: row lr (q-row r0+lr), stride 1036 ushorts; RRF[lr*1036+e] = RR[r0+lr][e]*log2e.
// bias read: d = c - r; off = d<=0 ? 1023+d : 1034+d  (d==1 -> zero slot 1035; d>=2 -> row lr+1, e=d-2)
__global__ __launch_bounds__(256) void attn7(
    const ushort* __restrict__ qkv, const ushort* __restrict__ Er,
    const ushort* __restrict__ Vt, ushort* __restrict__ out)
{
  const int bid0 = blockIdx.x;
  const int swz = (bid0 & 7)*256 + (bid0 >> 3);     // 8 heads' blocks per XCD
  const int bh = swz >> 5, b = bh >> 4, h = bh & 15;
  const int rt = swz & 31;
  const int r0 = rt*32;
  const int tid = threadIdx.x, w = tid >> 6, lane = tid & 63;
  const int l31 = lane & 31, hi = lane >> 5;

  __shared__ __align__(16) ushort RRF[34176];        // 33 x 1036 (row 32 only e<=1023)
  ushort* Obuf = RRF;                                 // aliased after phase-2 barrier: [4][32][68]
  float*  ml   = (float*)(RRF + 8704);                // [4][2][32]

  const ushort* Qp = qkv + (size_t)b*1024*3200 + h*64;
  const ushort* Kp = Qp + 1024;
  const ushort* Vp = Vt + (size_t)bh*64*1152;

  const int r = r0 + l31;
  short8 qf0 = *(const short8*)(Qp + (size_t)r*3200 +      hi*8);
  short8 qf1 = *(const short8*)(Qp + (size_t)r*3200 + 16 + hi*8);
  short8 qf2 = *(const short8*)(Qp + (size_t)r*3200 + 32 + hi*8);
  short8 qf3 = *(const short8*)(Qp + (size_t)r*3200 + 48 + hi*8);

  if (tid < 32) RRF[tid*1036 + 1035] = 0;            // diagonal-zero slots

  // Phase 1: RR rows r0..r0+31 (wave w covers e-quarter w*256..+256)
  for (int t=0; t<8; ++t){
    const int e0 = w*256 + t*32;
    const ushort* ep = Er + (size_t)(e0 + l31)*64 + hi*8;
    short8 ea0 = *(const short8*)(ep);
    short8 ea1 = *(const short8*)(ep + 16);
    short8 ea2 = *(const short8*)(ep + 32);
    short8 ea3 = *(const short8*)(ep + 48);
    f32x16 acc = {};
    acc = mfma32(ea0, qf0, acc);
    acc = mfma32(ea1, qf1, acc);
    acc = mfma32(ea2, qf2, acc);
    acc = mfma32(ea3, qf3, acc);
    #pragma unroll
    for (int q=0;q<4;q++){
      int e = e0 + 8*q + 4*hi;
      uint2 wv;
      wv.x = cvtpk(acc[4*q+0]*1.4426950408f, acc[4*q+1]*1.4426950408f);
      wv.y = cvtpk(acc[4*q+2]*1.4426950408f, acc[4*q+3]*1.4426950408f);
      *(uint2*)&RRF[l31*1036 + e] = wv;
    }
  }
  // extra row r0+32 (upper-diagonal source for q-row r0+31): VALU dot, 4 e per thread
  {
    const int q32r = min(r0 + 32, 1023);             // r0=992 row never read; clamp for safety
    const ushort* q32 = Qp + (size_t)q32r*3200;
    const int e4 = tid*4;
    float a[4] = {0.f,0.f,0.f,0.f};
    #pragma unroll
    for (int c8=0;c8<8;c8++){
      short8 qv = *(const short8*)(q32 + c8*8);
      float qx[8];
      #pragma unroll
      for (int i=0;i<8;i++) qx[i] = bf2f(((ushort*)&qv)[i]);
      #pragma unroll
      for (int e=0;e<4;e++){
        short8 ev = *(const short8*)(Er + (size_t)(e4+e)*64 + c8*8);
        #pragma unroll
        for (int i=0;i<8;i++) a[e] = fmaf(qx[i], bf2f(((ushort*)&ev)[i]), a[e]);
      }
    }
    uint2 wv;
    wv.x = cvtpk(a[0]*1.4426950408f, a[1]*1.4426950408f);
    wv.y = cvtpk(a[2]*1.4426950408f, a[3]*1.4426950408f);
    *(uint2*)&RRF[32*1036 + e4] = wv;
  }
  __syncthreads();

  // Phase 2: flash over this wave's kv quarter (8 tiles of 32), in-register softmax
  const int rbase = l31*1036;
  const int kvbase = w*256;
  f32x16 O0 = {}, O1 = {};
  float m = -3e38f, lsum = 0.f;

  short8 kA0 = *(const short8*)(Kp + (size_t)(kvbase + l31)*3200 +      hi*8);
  short8 kA1 = *(const short8*)(Kp + (size_t)(kvbase + l31)*3200 + 16 + hi*8);
  short8 kA2 = *(const short8*)(Kp + (size_t)(kvbase + l31)*3200 + 32 + hi*8);
  short8 kA3 = *(const short8*)(Kp + (size_t)(kvbase + l31)*3200 + 48 + hi*8);
  short8 kB0, kB1, kB2, kB3;

  auto step = [&](short8& ka0, short8& ka1, short8& ka2, short8& ka3,
                  short8& kn0, short8& kn1, short8& kn2, short8& kn3, int t){
    const int c0 = kvbase + t*32;
    if (t < 7){
      const ushort* kp = Kp + (size_t)(c0 + 32 + l31)*3200 + hi*8;
      kn0 = *(const short8*)(kp);
      kn1 = *(const short8*)(kp + 16);
      kn2 = *(const short8*)(kp + 32);
      kn3 = *(const short8*)(kp + 48);
    }
    // bias reads (hoisted; hide under QK MFMAs)
    ushort bs[16];
    #pragma unroll
    for (int q=0;q<4;q++)
      #pragma unroll
      for (int j=0;j<4;j++){
        int c = c0 + 8*q + 4*hi + j;
        int d = c - r;
        int off = (d<=0) ? (1023+d) : (1034+d);
        bs[4*q+j] = RRF[rbase + off];
      }
    short8 v00 = *(const short8*)(Vp + (size_t)l31*1152      + c0 +      hi*8);
    short8 v01 = *(const short8*)(Vp + (size_t)l31*1152      + c0 + 16 + hi*8);
    short8 v10 = *(const short8*)(Vp + (size_t)(32+l31)*1152 + c0 +      hi*8);
    short8 v11 = *(const short8*)(Vp + (size_t)(32+l31)*1152 + c0 + 16 + hi*8);
    f32x16 S = {};
    S = mfma32(ka0, qf0, S);
    S = mfma32(ka1, qf1, S);
    S = mfma32(ka2, qf2, S);
    S = mfma32(ka3, qf3, S);
    float p[16];
    float tmax = -3e38f;
    #pragma unroll
    for (int i=0;i<16;i++){
      float v = fmaf(S[i], 0.18033688f, bf2f(bs[i]));
      p[i] = v;
      tmax = fmaxf(tmax, v);
    }
    tmax = fmaxf(tmax, __shfl_xor(tmax, 32, 64));
    if (!__all(tmax <= m + 8.f)){
      float mn = fmaxf(m, tmax);
      float scl = __builtin_amdgcn_exp2f(m - mn);
      m = mn; lsum *= scl;
      #pragma unroll
      for (int i=0;i<16;i++){ O0[i]*=scl; O1[i]*=scl; }
    }
    float tsum = 0.f;
    #pragma unroll
    for (int i=0;i<16;i++){ p[i] = __builtin_amdgcn_exp2f(p[i]-m); tsum += p[i]; }
    lsum += tsum;
    uint W00=cvtpk(p[0],p[1]),   W01=cvtpk(p[2],p[3]);
    uint W10=cvtpk(p[4],p[5]),   W11=cvtpk(p[6],p[7]);
    uint W20=cvtpk(p[8],p[9]),   W21=cvtpk(p[10],p[11]);
    uint W30=cvtpk(p[12],p[13]), W31=cvtpk(p[14],p[15]);
    uint x00 = (uint)__shfl_xor((int)(hi? W00 : W10), 32, 64);
    uint x01 = (uint)__shfl_xor((int)(hi? W01 : W11), 32, 64);
    uint x10 = (uint)__shfl_xor((int)(hi? W20 : W30), 32, 64);
    uint x11 = (uint)__shfl_xor((int)(hi? W21 : W31), 32, 64);
    union { uint u[4]; short8 v; } pf0, pf1;
    pf0.u[0] = hi ? x00 : W00;  pf0.u[1] = hi ? x01 : W01;
    pf0.u[2] = hi ? W10 : x00;  pf0.u[3] = hi ? W11 : x01;
    pf1.u[0] = hi ? x10 : W20;  pf1.u[1] = hi ? x11 : W21;
    pf1.u[2] = hi ? W30 : x10;  pf1.u[3] = hi ? W31 : x11;
    O0 = mfma32(v00, pf0.v, O0);
    O0 = mfma32(v01, pf1.v, O0);
    O1 = mfma32(v10, pf0.v, O1);
    O1 = mfma32(v11, pf1.v, O1);
  };
  for (int t=0;t<8;t+=2){
    step(kA0,kA1,kA2,kA3, kB0,kB1,kB2,kB3, t);
    step(kB0,kB1,kB2,kB3, kA0,kA1,kA2,kA3, t+1);
  }
  lsum = lsum + __shfl_xor(lsum, 32, 64);

  __syncthreads();   // all RRF bias reads done; safe to alias
  // write per-wave partials (bf16) + m/l
  #pragma unroll
  for (int q=0;q<4;q++){
    int d = 8*q + 4*hi;
    uint2 w0, w1;
    w0.x = cvtpk(O0[4*q+0], O0[4*q+1]); w0.y = cvtpk(O0[4*q+2], O0[4*q+3]);
    w1.x = cvtpk(O1[4*q+0], O1[4*q+1]); w1.y = cvtpk(O1[4*q+2], O1[4*q+3]);
    *(uint2*)&Obuf[(w*32 + l31)*68 + d] = w0;
    *(uint2*)&Obuf[(w*32 + l31)*68 + 32 + d] = w1;
  }
  if (hi == 0){ ml[(w*2+0)*32 + l31] = m; ml[(w*2+1)*32 + l31] = lsum; }
  __syncthreads();
  // 4-way merge: thread = (row, 8-dim segment)
  {
    const int row = tid >> 3, ds8 = (tid & 7)*8;
    float M = ml[0*64 + row];
    #pragma unroll
    for (int w2=1;w2<4;w2++) M = fmaxf(M, ml[w2*64 + row]);
    float den = 0.f, num[8] = {0.f,0.f,0.f,0.f,0.f,0.f,0.f,0.f};
    #pragma unroll
    for (int w2=0;w2<4;w2++){
      float e2 = __builtin_amdgcn_exp2f(ml[w2*64 + row] - M);
      den += ml[w2*64 + 32 + row]*e2;
      uint2 o0 = *(const uint2*)&Obuf[(w2*32 + row)*68 + ds8];
      uint2 o1 = *(const uint2*)&Obuf[(w2*32 + row)*68 + ds8 + 4];
      const ushort* ou0 = (const ushort*)&o0;
      const ushort* ou1 = (const ushort*)&o1;
      #pragma unroll
      for (int i=0;i<4;i++){ num[i] += bf2f(ou0[i])*e2; num[4+i] += bf2f(ou1[i])*e2; }
    }
    float inv = 1.f/den;
    union { uint u[4]; short8 v; } ov;
    ov.u[0] = cvtpk(num[0]*inv, num[1]*inv);
    ov.u[1] = cvtpk(num[2]*inv, num[3]*inv);
    ov.u[2] = cvtpk(num[4]*inv, num[5]*inv);
    ov.u[3] = cvtpk(num[6]*inv, num[7]*inv);
    *(short8*)&out[((size_t)(b*1024 + r0 + row))*1152 + h*64 + ds8] = ov.v;
  }
}

extern "C" void kernel_launch(void* const* d_in, const int* in_sizes, int n_in,
                              void* d_out, int out_size, void* d_ws, size_t ws_size,
                              hipStream_t stream)
{
  const float* x    = (const float*)d_in[0];
  const float* t    = (const float*)d_in[1];
  const float* ln1g = (const float*)d_in[2];
  const float* ln1b = (const float*)d_in[3];
  const float* qkvw = (const float*)d_in[4];
  const float* qkvb = (const float*)d_in[5];
  const float* timew= (const float*)d_in[6];
  const float* timeb= (const float*)d_in[7];
  const float* outw = (const float*)d_in[8];
  const float* outbv= (const float*)d_in[9];
  const float* Er   = (const float*)d_in[10];
  const float* ln2g = (const float*)d_in[11];
  const float* ln2b = (const float*)d_in[12];
  const float* ff1w = (const float*)d_in[13];
  const float* ff1b = (const float*)d_in[14];
  const float* ff2w = (const float*)d_in[15];
  const float* ff2b = (const float*)d_in[16];
  float* o = (float*)d_out;

  char* ws = (char*)d_ws;
  ushort* qkvw_t = (ushort*)(ws);              // [3072][1152]
  ushort* outw_t = (ushort*)(ws + 7077888);    // [1024][1152]
  ushort* ff1w_t = (ushort*)(ws + 9437184);    // [4096][1152]
  ushort* ff2w_t = (ushort*)(ws + 18874368);   // [1024][4224]
  ushort* er_b   = (ushort*)(ws + 27525120);   // [1024][64]
  float*  tq     = (float*) (ws + 27656192);   // [4][3072]
  ushort* bufA   = (ushort*)(ws + 27705344);   // [4096][1152]
  ushort* vt     = (ushort*)(ws + 37142528);   // [4096][1152]
  ushort* bufB   = (ushort*)(ws + 46579712);   // [4096][4224] (qkv at stride 3200 / ff1o at 4224)

  wt_cvt<<<dim3(48,16),256,0,stream>>>(qkvw, qkvw_t, 1024, 3072, 1152);
  wt_cvt<<<dim3(16,16),256,0,stream>>>(outw, outw_t, 1024, 1024, 1152);
  wt_cvt<<<dim3(64,16),256,0,stream>>>(ff1w, ff1w_t, 1024, 4096, 1152);
  wt_cvt<<<dim3(16,64),256,0,stream>>>(ff2w, ff2w_t, 4096, 1024, 4224);
  cvt_f2b<<<256,256,0,stream>>>(Er, er_b, 65536);

  ln_rows<<<4096,256,0,stream>>>(x, ln1g, ln1b, bufA, 1152);
  tq_gemm2<<<48,256,0,stream>>>(t, timew, timeb, tq);
  gemm4<0,128><<<768,256,0,stream>>>(bufA, qkvw_t, qkvb, tq, bufB, nullptr,
                                     1024, 1152, 1152, 3200, 3072, 24);
  vt_k<<<dim3(16,64),256,0,stream>>>(bufB, vt);
  attn7<<<2048,256,0,stream>>>(bufB, er_b, vt, bufA);
  gemm4<1,64><<<512,256,0,stream>>>(bufA, outw_t, outbv, x, nullptr, o,
                                    1024, 1152, 1152, 1024, 1024, 16);
  ln_rows<<<4096,256,0,stream>>>(o, ln2g, ln2b, bufA, 1152);
  gemm4<2,128><<<1024,256,0,stream>>>(bufA, ff1w_t, ff1b, nullptr, bufB, nullptr,
                                      1024, 1152, 1152, 4224, 0, 32);
  gemm4<1,64><<<512,256,0,stream>>>(bufB, ff2w_t, ff2b, o, nullptr, o,
                                    4096, 4224, 4224, 1024, 1024, 16);
}